// Round 11
// baseline (972.684 us; speedup 1.0000x reference)
//
#include <hip/hip_runtime.h>
#include <stdint.h>

#define NN 50000
#define QWORDS 25600000   // N*F words; q_out region. mu_out region starts here.

typedef __attribute__((ext_vector_type(8))) short bf16x8;
typedef __attribute__((ext_vector_type(4))) float f32x4;

__device__ __forceinline__ uint32_t f2bf(float x){
  uint32_t u = __builtin_bit_cast(uint32_t, x);
  u += 0x7FFFu + ((u >> 16) & 1u);          // RNE
  return u >> 16;
}
__device__ __forceinline__ float bf2f(uint32_t b){
  uint32_t u = b << 16;
  return __builtin_bit_cast(float, u);
}
__device__ __forceinline__ void gload16(const uint16_t* g, uint16_t* l){
  __builtin_amdgcn_global_load_lds(
      (const __attribute__((address_space(1))) uint32_t*)g,
      (__attribute__((address_space(3))) uint32_t*)l, 16, 0, 0);
}
__device__ __forceinline__ f32x4 mfma16(bf16x8 a, bf16x8 b, f32x4 c){
  return __builtin_amdgcn_mfma_f32_16x16x32_bf16(a, b, c, 0, 0, 0);
}

#define FENCE() asm volatile("" ::: "memory")

// ---------------- K0: weights f32 -> bf16 into ws ----------------
// layout (u16): [0,524288) W_mix | [524288,1048576) W1 | [1048576,1835008) W2
// optional [1835008, +76800000) muW bf16 (if ws large enough)
__global__ void k_convert(const float* __restrict__ wmix, const float* __restrict__ w1,
                          const float* __restrict__ w2, uint16_t* __restrict__ dst){
  int i = blockIdx.x * 256 + threadIdx.x;   // float4 index; grid covers exactly 458752
  int e = i << 2;
  const float* s; int o;
  if (e < 524288)       { s = wmix; o = e; }
  else if (e < 1048576) { s = w1;   o = e - 524288; }
  else                  { s = w2;   o = e - 1048576; }
  f32x4 v = *(const f32x4*)(s + o);
  uint2 pk;
  pk.x = f2bf(v[0]) | (f2bf(v[1]) << 16);
  pk.y = f2bf(v[2]) | (f2bf(v[3]) << 16);
  *(uint2*)(dst + e) = pk;
}

// ---------------- K1 (fallback, f32 muW) -------------------------------------
__global__ __launch_bounds__(512, 4)
void k_gemm1(const float* __restrict__ mu, const uint16_t* __restrict__ wmixb,
             uint16_t* __restrict__ qh, float* __restrict__ muW){
  __shared__ uint16_t As[2][12288];   // 192x64 (r = d*64+nrow), 2x24KB
  __shared__ uint16_t Bs[2][8192];    // 128x64, 2x16KB
  const int tid  = threadIdx.x;
  const int lane = tid & 63;
  const int w    = tid >> 6;          // 0..7
  const int wn   = w & 3;             // n-quarter (16 rows)
  const int wf   = w >> 2;            // f-half (2 col-pairs)
  const int orig = blockIdx.x;
  const int j    = (orig & 7) * 782 + (orig >> 3);   // bijective XCD chunking
  const int f0   = (j & 7) * 64;
  const int n0   = (j >> 3) * 64;
  const int lrow = tid >> 4;          // 0..31
  const int lcol = (tid & 15) * 4;    // f32/u16 col base

  f32x4 ar[6];
  auto A_LOAD = [&](int ks){
    const int k0 = ks * 64;
    #pragma unroll
    for (int p=0; p<6; ++p){
      int r = p*32 + lrow;            // 0..191 = d*64 + nrow
      int d = r >> 6, nrow = r & 63;
      int n = n0 + nrow;
      int g = (n < NN ? n : NN-1)*3 + d;
      ar[p] = *(const f32x4*)(mu + (size_t)g*512 + k0 + lcol);
    }
  };
  auto A_WRITE = [&](int buf){
    #pragma unroll
    for (int p=0; p<6; ++p){
      int r = p*32 + lrow;
      f32x4 v = ar[p];
      uint2 pk;
      pk.x = f2bf(v[0]) | (f2bf(v[1]) << 16);
      pk.y = f2bf(v[2]) | (f2bf(v[3]) << 16);
      *(uint2*)&As[buf][r*64 + (lcol ^ ((r&7)<<3))] = pk;
    }
  };
  auto B_ISSUE = [&](int ks, int buf){
    const int k0 = ks * 64;
    #pragma unroll
    for (int jj=0; jj<2; ++jj){
      int jb = w*2 + jj;                 // 0..15
      int row = jb*8 + (lane>>3);
      int g = (row < 64) ? (f0 + row) : (448 + f0 + row);
      int srcc = ((lane&7) ^ ((lane>>3)&7)) * 8;
      gload16(wmixb + (size_t)g*512 + k0 + srcc, &Bs[buf][jb*512]);
    }
  };

  const f32x4 z4 = {0.f,0.f,0.f,0.f};
  f32x4 acc[3][4];
  #pragma unroll
  for (int d=0; d<3; ++d)
    #pragma unroll
    for (int nt=0; nt<4; ++nt) acc[d][nt] = z4;

  A_LOAD(0); B_ISSUE(0, 0); A_WRITE(0);
  for (int ks=0; ks<8; ++ks){
    const int cur = ks & 1;
    __syncthreads();
    if (ks < 7){ A_LOAD(ks+1); B_ISSUE(ks+1, cur^1); }
    #pragma unroll
    for (int kf=0; kf<2; ++kf){
      int kc = kf*32 + (lane>>4)*8;
      bf16x8 af[3];
      #pragma unroll
      for (int d=0; d<3; ++d){
        int r = d*64 + wn*16 + (lane&15);
        af[d] = *(const bf16x8*)&As[cur][r*64 + (kc ^ ((r&7)<<3))];
      }
      #pragma unroll
      for (int nt=0; nt<4; ++nt){
        int ntg = wf*2 + (nt&1) + (nt>>1)*4;
        int rr = ntg*16 + (lane&15);
        bf16x8 bf = *(const bf16x8*)&Bs[cur][rr*64 + (kc ^ ((rr&7)<<3))];
        #pragma unroll
        for (int d=0; d<3; ++d)
          acc[d][nt] = mfma16(bf, af[d], acc[d][nt]);   // SWAPPED: D[f, n]
      }
    }
    if (ks < 7) A_WRITE(cur^1);
  }

  const int rb4 = (lane >> 4) * 4;
  const int nthr = n0 + wn*16 + (lane & 15);
  if (nthr < NN){
    #pragma unroll
    for (int c=0; c<2; ++c){
      int f = f0 + (wf*2 + c)*16 + rb4;
      uint2 pkv, pkd; f32x4 u0v, u1v, u2v;
      uint32_t vb[4], db[4];
      #pragma unroll
      for (int p=0; p<4; ++p){
        float v0 = acc[0][c][p],   v1 = acc[1][c][p],   v2 = acc[2][c][p];
        float u0 = acc[0][c+2][p], u1 = acc[1][c+2][p], u2 = acc[2][c+2][p];
        float vn = sqrtf(v0*v0 + v1*v1 + v2*v2 + 1e-8f);
        float dt = v0*u0 + v1*u1 + v2*u2;
        vb[p] = f2bf(vn); db[p] = f2bf(dt);
        u0v[p] = u0; u1v[p] = u1; u2v[p] = u2;
      }
      pkv.x = vb[0] | (vb[1] << 16); pkv.y = vb[2] | (vb[3] << 16);
      pkd.x = db[0] | (db[1] << 16); pkd.y = db[2] | (db[3] << 16);
      *(uint2*)(qh + (size_t)nthr*1024 + f)       = pkv;
      *(uint2*)(qh + (size_t)nthr*1024 + 512 + f) = pkd;
      size_t mb = (size_t)nthr*1536 + f;
      *(f32x4*)(muW + mb)        = u0v;
      *(f32x4*)(muW + mb + 512)  = u1v;
      *(f32x4*)(muW + mb + 1024) = u2v;
    }
  }
}

// ---------------- K1b (round-10 proven): muW stored bf16 in ws ---------------
__global__ __launch_bounds__(512, 4)
void k_gemm1b(const float* __restrict__ mu, const uint16_t* __restrict__ wmixb,
              uint16_t* __restrict__ qh, uint16_t* __restrict__ mw16){
  __shared__ uint16_t As[2][12288];
  __shared__ uint16_t Bs[2][8192];
  const int tid  = threadIdx.x;
  const int lane = tid & 63;
  const int w    = tid >> 6;
  const int wn   = w & 3;
  const int wf   = w >> 2;
  const int orig = blockIdx.x;
  const int j    = (orig & 7) * 782 + (orig >> 3);
  const int f0   = (j & 7) * 64;
  const int n0   = (j >> 3) * 64;
  const int lrow = tid >> 4;
  const int lcol = (tid & 15) * 4;

  f32x4 ar[6];
  auto A_LOAD = [&](int ks){
    const int k0 = ks * 64;
    #pragma unroll
    for (int p=0; p<6; ++p){
      int r = p*32 + lrow;
      int d = r >> 6, nrow = r & 63;
      int n = n0 + nrow;
      int g = (n < NN ? n : NN-1)*3 + d;
      ar[p] = *(const f32x4*)(mu + (size_t)g*512 + k0 + lcol);
    }
  };
  auto A_WRITE = [&](int buf){
    #pragma unroll
    for (int p=0; p<6; ++p){
      int r = p*32 + lrow;
      f32x4 v = ar[p];
      uint2 pk;
      pk.x = f2bf(v[0]) | (f2bf(v[1]) << 16);
      pk.y = f2bf(v[2]) | (f2bf(v[3]) << 16);
      *(uint2*)&As[buf][r*64 + (lcol ^ ((r&7)<<3))] = pk;
    }
  };
  auto B_ISSUE = [&](int ks, int buf){
    const int k0 = ks * 64;
    #pragma unroll
    for (int jj=0; jj<2; ++jj){
      int jb = w*2 + jj;
      int row = jb*8 + (lane>>3);
      int g = (row < 64) ? (f0 + row) : (448 + f0 + row);
      int srcc = ((lane&7) ^ ((lane>>3)&7)) * 8;
      gload16(wmixb + (size_t)g*512 + k0 + srcc, &Bs[buf][jb*512]);
    }
  };

  const f32x4 z4 = {0.f,0.f,0.f,0.f};
  f32x4 acc[3][4];
  #pragma unroll
  for (int d=0; d<3; ++d)
    #pragma unroll
    for (int nt=0; nt<4; ++nt) acc[d][nt] = z4;

  A_LOAD(0); B_ISSUE(0, 0); A_WRITE(0);
  for (int ks=0; ks<8; ++ks){
    const int cur = ks & 1;
    __syncthreads();
    if (ks < 7){ A_LOAD(ks+1); B_ISSUE(ks+1, cur^1); }
    #pragma unroll
    for (int kf=0; kf<2; ++kf){
      int kc = kf*32 + (lane>>4)*8;
      bf16x8 af[3];
      #pragma unroll
      for (int d=0; d<3; ++d){
        int r = d*64 + wn*16 + (lane&15);
        af[d] = *(const bf16x8*)&As[cur][r*64 + (kc ^ ((r&7)<<3))];
      }
      #pragma unroll
      for (int nt=0; nt<4; ++nt){
        int ntg = wf*2 + (nt&1) + (nt>>1)*4;
        int rr = ntg*16 + (lane&15);
        bf16x8 bf = *(const bf16x8*)&Bs[cur][rr*64 + (kc ^ ((rr&7)<<3))];
        #pragma unroll
        for (int d=0; d<3; ++d)
          acc[d][nt] = mfma16(bf, af[d], acc[d][nt]);
      }
    }
    if (ks < 7) A_WRITE(cur^1);
  }

  const int rb4 = (lane >> 4) * 4;
  const int nthr = n0 + wn*16 + (lane & 15);
  if (nthr < NN){
    #pragma unroll
    for (int c=0; c<2; ++c){
      int f = f0 + (wf*2 + c)*16 + rb4;
      uint2 pkv, pkd, pw0, pw1, pw2;
      uint32_t vb[4], db[4], w0[4], w1[4], w2[4];
      #pragma unroll
      for (int p=0; p<4; ++p){
        float v0 = acc[0][c][p],   v1 = acc[1][c][p],   v2 = acc[2][c][p];
        float u0 = acc[0][c+2][p], u1 = acc[1][c+2][p], u2 = acc[2][c+2][p];
        float vn = sqrtf(v0*v0 + v1*v1 + v2*v2 + 1e-8f);
        float dt = v0*u0 + v1*u1 + v2*u2;
        vb[p] = f2bf(vn); db[p] = f2bf(dt);
        w0[p] = f2bf(u0); w1[p] = f2bf(u1); w2[p] = f2bf(u2);
      }
      pkv.x = vb[0] | (vb[1] << 16); pkv.y = vb[2] | (vb[3] << 16);
      pkd.x = db[0] | (db[1] << 16); pkd.y = db[2] | (db[3] << 16);
      pw0.x = w0[0] | (w0[1] << 16); pw0.y = w0[2] | (w0[3] << 16);
      pw1.x = w1[0] | (w1[1] << 16); pw1.y = w1[2] | (w1[3] << 16);
      pw2.x = w2[0] | (w2[1] << 16); pw2.y = w2[2] | (w2[3] << 16);
      *(uint2*)(qh + (size_t)nthr*1024 + f)       = pkv;
      *(uint2*)(qh + (size_t)nthr*1024 + 512 + f) = pkd;
      size_t mb = (size_t)nthr*1536 + f;
      *(uint2*)(mw16 + mb)        = pw0;
      *(uint2*)(mw16 + mb + 512)  = pw1;
      *(uint2*)(mw16 + mb + 1024) = pw2;
    }
  }
}

// ---------------- K2 v2 (round-7 proven): 512 threads ------------------------
__global__ __launch_bounds__(512, 4)
void k_gemm2(const float* __restrict__ q, const uint16_t* __restrict__ w1b,
             const float* __restrict__ b1, uint16_t* __restrict__ qh){
  __shared__ uint16_t A2[2][2048];    // 64x32, 2x4KB
  __shared__ uint16_t B2[2][16384];   // 512x32, 2x32KB
  const int tid  = threadIdx.x;
  const int lane = tid & 63;
  const int w    = tid >> 6;          // 0..7
  const int wm   = w >> 2;            // 0..1 (32-row half)
  const int wn   = w & 3;             // 0..3 (128-col quarter)
  const int n0   = blockIdx.x * 64;

  f32x4 qa;
  auto QA_LOAD = [&](int s){
    int k0 = s*32;
    int row = tid >> 3, ch = tid & 7;
    int nc = (n0 + row < NN) ? n0 + row : NN-1;
    qa = *(const f32x4*)(q + (size_t)nc*512 + k0 + ch*4);
  };
  auto QA_WRITE = [&](int buf){
    int row = tid >> 3, ch = tid & 7;
    uint2 pk;
    pk.x = f2bf(qa[0]) | (f2bf(qa[1]) << 16);
    pk.y = f2bf(qa[2]) | (f2bf(qa[3]) << 16);
    *(uint2*)&A2[buf][row*32 + (((ch>>1) ^ (row&3))<<3) + (ch&1)*4] = pk;
  };
  auto VA_ISSUE = [&](int s, int buf){
    if (w < 4){
      int k0v = (s-16)*32;
      int row = w*16 + (lane>>2);
      int nc = (n0 + row < NN) ? n0 + row : NN-1;
      int srcch = (lane&3) ^ (row&3);
      gload16(qh + (size_t)nc*1024 + k0v + srcch*8, &A2[buf][w*512]);
    }
  };
  auto B_ISSUE = [&](int s, int buf){
    int k0 = s*32;
    #pragma unroll
    for (int jj=0; jj<4; ++jj){
      int j = w*4 + jj;
      int row = j*16 + (lane>>2);
      int srcch = (lane&3) ^ (row&3);
      gload16(w1b + (size_t)row*1024 + k0 + srcch*8, &B2[buf][j*512]);
    }
  };

  const f32x4 z4 = {0.f,0.f,0.f,0.f};
  f32x4 acc2[2][8];
  #pragma unroll
  for (int mt=0; mt<2; ++mt)
    #pragma unroll
    for (int nt=0; nt<8; ++nt) acc2[mt][nt] = z4;

  QA_LOAD(0); B_ISSUE(0, 0); QA_WRITE(0);
  for (int s=0; s<32; ++s){
    const int cur = s & 1;
    __syncthreads();
    if (s < 31){
      if (s+1 < 16) QA_LOAD(s+1); else VA_ISSUE(s+1, cur^1);
      B_ISSUE(s+1, cur^1);
    }
    {
      int kc = (lane>>4)*8;
      bf16x8 a[2];
      #pragma unroll
      for (int mt=0; mt<2; ++mt){
        int r = wm*32 + mt*16 + (lane&15);
        a[mt] = *(const bf16x8*)&A2[cur][r*32 + (kc ^ ((r&3)<<3))];
      }
      #pragma unroll
      for (int nt=0; nt<8; ++nt){
        int rr = wn*128 + nt*16 + (lane&15);
        bf16x8 b = *(const bf16x8*)&B2[cur][rr*32 + (kc ^ ((rr&3)<<3))];
        acc2[0][nt] = mfma16(a[0], b, acc2[0][nt]);
        acc2[1][nt] = mfma16(a[1], b, acc2[1][nt]);
      }
    }
    if (s < 31 && s+1 < 16) QA_WRITE(cur^1);
  }

  const int rb4 = (lane >> 4) * 4;
  #pragma unroll
  for (int nt=0; nt<8; ++nt){
    int col = wn*128 + nt*16 + (lane&15);
    float bb = b1[col];
    #pragma unroll
    for (int mt=0; mt<2; ++mt)
      #pragma unroll
      for (int j=0; j<4; ++j){
        int n = n0 + wm*32 + mt*16 + rb4 + j;
        if (n < NN){
          float x = acc2[mt][nt][j] + bb;
          float sv = x / (1.f + __expf(-x));
          qh[(size_t)n*1024 + col] = (uint16_t)f2bf(sv);
        }
      }
  }
}

// ---------------- K3 v9: 16-row blocks, K-step 32, 40KB LDS -> 4 blocks/CU ---
// 256 threads (4 waves, wave w owns f-group w*16 per 64-strip). 16 phases/it,
// 3 MFMA/phase. Same counted-vmcnt pattern as v8 ({4/0,5,3,3,0..}) since
// per-phase issue counts are unchanged (B=3, E0=5, E1=3, E2=3, stores=4).
// mwv from read-only ws (bf16) -> no in-place hazard. grid = 50000/16 = 3125.
__global__ __launch_bounds__(256, 4)
void k_gemm3c(const float* __restrict__ q, const float* __restrict__ mu,
              const uint16_t* __restrict__ w2b, const float* __restrict__ b2,
              float* __restrict__ dout, const uint16_t* __restrict__ mw16){
  __shared__ uint16_t Hs[16*512];     // 16KB
  __shared__ uint16_t B3[2][6144];    // 2x12KB ring (192 rows x 32 k)
  const int tid  = threadIdx.x;
  const int lane = tid & 63;
  const int w    = tid >> 6;          // 0..3 (f-group)
  const int n0   = blockIdx.x * 16;
  const uint16_t* qh = (const uint16_t*)dout;
  float* mout = dout + (size_t)QWORDS;
  const int l15 = lane & 15;
  const int rb4 = (lane >> 4) * 4;
  const f32x4 z4 = {0.f,0.f,0.f,0.f};

  // prologue: Hs 16 rows (h only), 4 issues/wave
  #pragma unroll
  for (int i=0; i<4; ++i){
    int row = w*4 + i;
    int nc2 = (n0 + row < NN) ? n0 + row : NN-1;
    gload16(qh + (size_t)nc2*1024 + (size_t)((lane ^ (row&7))*8), &Hs[row*512]);
  }

  auto B_ISSUE = [&](int it, int ks, uint16_t* slot){
    #pragma unroll
    for (int jj=0; jj<3; ++jj){
      int j = w*3 + jj;               // 0..11
      int rr = j*16 + (lane>>2);      // 0..191
      int s3 = rr >> 6, fi = rr & 63;
      int g = s3*512 + it*64 + fi;
      int srcc = ((lane&3) ^ (rr&3)) * 8;
      gload16(w2b + (size_t)g*512 + ks*32 + srcc, slot + j*512);
    }
  };
  B_ISSUE(0, 0, B3[0]);

  const int nthr = n0 + l15;
  const int nc   = nthr < NN ? nthr : NN-1;

  f32x4 qv, bbv[3], muv[3], mwv[3];
  float dtv[4];
  int   fb = 0;
  f32x4 acc3[3];

#define K3C_MFMA(P) do{ \
    const uint16_t* bsl = B3[(P)&1]; \
    __builtin_amdgcn_s_setprio(1); \
    { \
      int r = l15; \
      int ch = ((P)*4 + (lane>>4)) ^ (r&7); \
      bf16x8 a = *(const bf16x8*)&Hs[r*512 + ch*8]; \
      _Pragma("unroll") \
      for (int s3=0; s3<3; ++s3){ \
        int rr = s3*64 + w*16 + l15; \
        int chb = (lane>>4) ^ (rr&3); \
        bf16x8 b = *(const bf16x8*)&bsl[rr*32 + chb*8]; \
        acc3[s3] = mfma16(b, a, acc3[s3]); \
      } \
    } \
    __builtin_amdgcn_s_setprio(0); \
  } while(0)

#define K3C_PHASE(P, WAIT) \
    asm volatile("s_waitcnt vmcnt(" #WAIT ")" ::: "memory"); \
    __builtin_amdgcn_s_barrier(); \
    B_ISSUE(it, (P)+1, B3[((P)+1)&1]); \
    FENCE(); \
    K3C_MFMA(P);

  #pragma unroll 1
  for (int it=0; it<8; ++it){
    // ---- p0 ----
    if (it) { asm volatile("s_waitcnt vmcnt(4)" ::: "memory"); }
    else    { asm volatile("s_waitcnt vmcnt(0)" ::: "memory"); }
    __builtin_amdgcn_s_barrier();
    B_ISSUE(it, 1, B3[1]);
    FENCE();
    {
      #pragma unroll
      for (int s3=0; s3<3; ++s3) acc3[s3] = z4;
      fb = it*64 + w*16 + rb4;
      bbv[0] = *(const f32x4*)(b2 + fb);
      bbv[1] = *(const f32x4*)(b2 + 512 + fb);
      bbv[2] = *(const f32x4*)(b2 + 1024 + fb);
      uint2 du = *(const uint2*)(qh + (size_t)nc*1024 + 512 + fb);
      dtv[0] = bf2f(du.x & 0xffff); dtv[1] = bf2f(du.x >> 16);
      dtv[2] = bf2f(du.y & 0xffff); dtv[3] = bf2f(du.y >> 16);
      qv = *(const f32x4*)(q + (size_t)nc*512 + fb);
    }
    FENCE();
    K3C_MFMA(0);

    // ---- p1 ----
    asm volatile("s_waitcnt vmcnt(5)" ::: "memory");
    __builtin_amdgcn_s_barrier();
    B_ISSUE(it, 2, B3[0]);
    FENCE();
    {
      size_t mb = (size_t)nc*1536 + fb;
      muv[0] = *(const f32x4*)(mu + mb);
      muv[1] = *(const f32x4*)(mu + mb + 512);
      muv[2] = *(const f32x4*)(mu + mb + 1024);
    }
    FENCE();
    K3C_MFMA(1);

    // ---- p2 ----
    asm volatile("s_waitcnt vmcnt(3)" ::: "memory");
    __builtin_amdgcn_s_barrier();
    B_ISSUE(it, 3, B3[1]);
    FENCE();
    {
      size_t mb = (size_t)nc*1536 + fb;
      uint2 a0 = *(const uint2*)(mw16 + mb);
      uint2 a1 = *(const uint2*)(mw16 + mb + 512);
      uint2 a2 = *(const uint2*)(mw16 + mb + 1024);
      mwv[0][0]=bf2f(a0.x&0xffff); mwv[0][1]=bf2f(a0.x>>16);
      mwv[0][2]=bf2f(a0.y&0xffff); mwv[0][3]=bf2f(a0.y>>16);
      mwv[1][0]=bf2f(a1.x&0xffff); mwv[1][1]=bf2f(a1.x>>16);
      mwv[1][2]=bf2f(a1.y&0xffff); mwv[1][3]=bf2f(a1.y>>16);
      mwv[2][0]=bf2f(a2.x&0xffff); mwv[2][1]=bf2f(a2.x>>16);
      mwv[2][2]=bf2f(a2.y&0xffff); mwv[2][3]=bf2f(a2.y>>16);
    }
    FENCE();
    K3C_MFMA(2);

    // ---- p3..p14 ----
    K3C_PHASE(3, 3)
    K3C_PHASE(4, 0)
    K3C_PHASE(5, 0)
    K3C_PHASE(6, 0)
    K3C_PHASE(7, 0)
    K3C_PHASE(8, 0)
    K3C_PHASE(9, 0)
    K3C_PHASE(10, 0)
    K3C_PHASE(11, 0)
    K3C_PHASE(12, 0)
    K3C_PHASE(13, 0)
    K3C_PHASE(14, 0)

    // ---- p15 ----
    asm volatile("s_waitcnt vmcnt(0)" ::: "memory");
    __builtin_amdgcn_s_barrier();
    if (it < 7) B_ISSUE(it+1, 0, B3[0]);
    FENCE();
    K3C_MFMA(15);
    if (nthr < NN){
      f32x4 qo, m0, m1, m2;
      #pragma unroll
      for (int p=0; p<4; ++p){
        float x0 = acc3[0][p] + bbv[0][p];
        float x1 = acc3[1][p] + bbv[1][p];
        float x2 = acc3[2][p] + bbv[2][p];
        qo[p] = qv[p] + x0 + x2*dtv[p];
        m0[p] = muv[0][p] + x1*mwv[0][p];
        m1[p] = muv[1][p] + x1*mwv[1][p];
        m2[p] = muv[2][p] + x1*mwv[2][p];
      }
      *(f32x4*)(dout + (size_t)nthr*512 + fb) = qo;
      size_t mb = (size_t)nthr*1536 + fb;
      *(f32x4*)(mout + mb)        = m0;
      *(f32x4*)(mout + mb + 512)  = m1;
      *(f32x4*)(mout + mb + 1024) = m2;
    }
  }
#undef K3C_PHASE
#undef K3C_MFMA
}

// ---------------- K3 (fallback, round-8): f32 muW in-place -------------------
__global__ __launch_bounds__(512, 4)
void k_gemm3(const float* __restrict__ q, const float* __restrict__ mu,
             const uint16_t* __restrict__ w2b, const float* __restrict__ b2,
             float* __restrict__ dout){
  __shared__ uint16_t Hs[32*512];     // 32KB
  __shared__ uint16_t B3[2][12288];   // 2x24KB ring
  const int tid  = threadIdx.x;
  const int lane = tid & 63;
  const int w    = tid >> 6;
  const int wm   = w >> 2;
  const int wn   = w & 3;
  const int n0   = blockIdx.x * 32;
  const uint16_t* qh = (const uint16_t*)dout;
  float* mout = dout + (size_t)QWORDS;
  const int l15 = lane & 15;
  const int rb4 = (lane >> 4) * 4;
  const f32x4 z4 = {0.f,0.f,0.f,0.f};

  #pragma unroll
  for (int i=0; i<4; ++i){
    int row = w*4 + i;
    int nc2 = (n0 + row < NN) ? n0 + row : NN-1;
    gload16(qh + (size_t)nc2*1024 + (size_t)((lane ^ (row&7))*8), &Hs[row*512]);
  }

  auto B_ISSUE = [&](int it, int ks, uint16_t* slot){
    #pragma unroll
    for (int jj=0; jj<3; ++jj){
      int jx = w*3 + jj;
      int rr = jx*8 + (lane>>3);
      int s3 = rr >> 6, fi = rr & 63;
      int g = s3*512 + it*64 + fi;
      gload16(w2b + (size_t)g*512 + ks*64 + ((lane&7) ^ (rr&7))*8, slot + jx*512);
    }
  };
  B_ISSUE(0, 0, B3[0]);

  const int nthr = n0 + wm*16 + l15;
  const int nc   = nthr < NN ? nthr : NN-1;

  f32x4 qv, bbv[3], muv[3], mwv[3];
  float dtv[4];
  int   fb = 0;
  f32x4 acc3[3];

#define K3_MFMA(KS) do{ \
    const uint16_t* bsl = B3[(KS)&1]; \
    __builtin_amdgcn_s_setprio(1); \
    _Pragma("unroll") \
    for (int kf=0; kf<2; ++kf){ \
      int r = wm*16 + l15; \
      int ch = ((KS)*8 + kf*4 + (lane>>4)) ^ (r&7); \
      bf16x8 a = *(const bf16x8*)&Hs[r*512 + ch*8]; \
      _Pragma("unroll") \
      for (int s3=0; s3<3; ++s3){ \
        int rr = s3*64 + wn*16 + l15; \
        int chb = (kf*4 + (lane>>4)) ^ (rr&7); \
        bf16x8 b = *(const bf16x8*)&bsl[rr*64 + chb*8]; \
        acc3[s3] = mfma16(b, a, acc3[s3]); \
      } \
    } \
    __builtin_amdgcn_s_setprio(0); \
  } while(0)

  #pragma unroll 1
  for (int it=0; it<8; ++it){
    if (it) { asm volatile("s_waitcnt vmcnt(4)" ::: "memory"); }
    else    { asm volatile("s_waitcnt vmcnt(0)" ::: "memory"); }
    __builtin_amdgcn_s_barrier();
    B_ISSUE(it, 1, B3[1]);
    FENCE();
    {
      #pragma unroll
      for (int s3=0; s3<3; ++s3) acc3[s3] = z4;
      fb = it*64 + wn*16 + rb4;
      bbv[0] = *(const f32x4*)(b2 + fb);
      bbv[1] = *(const f32x4*)(b2 + 512 + fb);
      bbv[2] = *(const f32x4*)(b2 + 1024 + fb);
      uint2 du = *(const uint2*)(qh + (size_t)nc*1024 + 512 + fb);
      dtv[0] = bf2f(du.x & 0xffff); dtv[1] = bf2f(du.x >> 16);
      dtv[2] = bf2f(du.y & 0xffff); dtv[3] = bf2f(du.y >> 16);
      qv = *(const f32x4*)(q + (size_t)nc*512 + fb);
    }
    FENCE();
    K3_MFMA(0);

    asm volatile("s_waitcnt vmcnt(5)" ::: "memory");
    __builtin_amdgcn_s_barrier();
    B_ISSUE(it, 2, B3[0]);
    FENCE();
    {
      size_t mb = (size_t)nc*1536 + fb;
      muv[0] = *(const f32x4*)(mu + mb);
      muv[1] = *(const f32x4*)(mu + mb + 512);
      muv[2] = *(const f32x4*)(mu + mb + 1024);
    }
    FENCE();
    K3_MFMA(1);

    asm volatile("s_waitcnt vmcnt(3)" ::: "memory");
    __builtin_amdgcn_s_barrier();
    B_ISSUE(it, 3, B3[1]);
    FENCE();
    {
      size_t mb = (size_t)nc*1536 + fb;
      mwv[0] = *(const f32x4*)(mout + mb);
      mwv[1] = *(const f32x4*)(mout + mb + 512);
      mwv[2] = *(const f32x4*)(mout + mb + 1024);
    }
    FENCE();
    K3_MFMA(2);

    asm volatile("s_waitcnt vmcnt(3)" ::: "memory");
    __builtin_amdgcn_s_barrier();
    B_ISSUE(it, 4, B3[0]);
    FENCE();
    K3_MFMA(3);

    asm volatile("s_waitcnt vmcnt(0)" ::: "memory");
    __builtin_amdgcn_s_barrier();
    B_ISSUE(it, 5, B3[1]);
    FENCE();
    K3_MFMA(4);

    asm volatile("s_waitcnt vmcnt(0)" ::: "memory");
    __builtin_amdgcn_s_barrier();
    B_ISSUE(it, 6, B3[0]);
    FENCE();
    K3_MFMA(5);

    asm volatile("s_waitcnt vmcnt(0)" ::: "memory");
    __builtin_amdgcn_s_barrier();
    B_ISSUE(it, 7, B3[1]);
    FENCE();
    K3_MFMA(6);

    asm volatile("s_waitcnt vmcnt(0)" ::: "memory");
    __builtin_amdgcn_s_barrier();
    if (it < 7) B_ISSUE(it+1, 0, B3[0]);
    FENCE();
    K3_MFMA(7);
    if (nthr < NN){
      f32x4 qo, m0, m1, m2;
      #pragma unroll
      for (int p=0; p<4; ++p){
        float x0 = acc3[0][p] + bbv[0][p];
        float x1 = acc3[1][p] + bbv[1][p];
        float x2 = acc3[2][p] + bbv[2][p];
        qo[p] = qv[p] + x0 + x2*dtv[p];
        m0[p] = muv[0][p] + x1*mwv[0][p];
        m1[p] = muv[1][p] + x1*mwv[1][p];
        m2[p] = muv[2][p] + x1*mwv[2][p];
      }
      *(f32x4*)(dout + (size_t)nthr*512 + fb) = qo;
      size_t mb = (size_t)nthr*1536 + fb;
      *(f32x4*)(mout + mb)        = m0;
      *(f32x4*)(mout + mb + 512)  = m1;
      *(f32x4*)(mout + mb + 1024) = m2;
    }
  }
#undef K3_MFMA
}

extern "C" void kernel_launch(void* const* d_in, const int* in_sizes, int n_in,
                              void* d_out, int out_size, void* d_ws, size_t ws_size,
                              hipStream_t stream){
  (void)in_sizes; (void)n_in; (void)out_size;
  const float* q    = (const float*)d_in[0];
  const float* mu   = (const float*)d_in[1];
  const float* wmix = (const float*)d_in[2];
  const float* w1   = (const float*)d_in[3];
  const float* b1   = (const float*)d_in[4];
  const float* w2   = (const float*)d_in[5];
  const float* b2   = (const float*)d_in[6];
  uint16_t* wb = (uint16_t*)d_ws;
  float* dout = (float*)d_out;

  hipLaunchKernelGGL(k_convert, dim3(1792), dim3(256), 0, stream, wmix, w1, w2, wb);

  const size_t need = ((size_t)1835008 + (size_t)NN*1536) * 2;   // 157.3 MB
  if (ws_size >= need){
    uint16_t* mw16 = wb + 1835008;
    hipLaunchKernelGGL(k_gemm1b, dim3(6256), dim3(512), 0, stream,
                       mu, wb, (uint16_t*)d_out, mw16);
    hipLaunchKernelGGL(k_gemm2, dim3(782), dim3(512), 0, stream,
                       q, wb + 524288, b1, (uint16_t*)d_out);
    hipLaunchKernelGGL(k_gemm3c, dim3(3125), dim3(256), 0, stream,
                       q, mu, wb + 1048576, b2, dout, mw16);
  } else {
    hipLaunchKernelGGL(k_gemm1, dim3(6256), dim3(512), 0, stream,
                       mu, wb, (uint16_t*)d_out, dout + (size_t)QWORDS);
    hipLaunchKernelGGL(k_gemm2, dim3(782), dim3(512), 0, stream,
                       q, wb + 524288, b1, (uint16_t*)d_out);
    hipLaunchKernelGGL(k_gemm3, dim3(1563), dim3(512), 0, stream,
                       q, mu, wb + 1048576, b2, dout);
  }
}

// Round 12
// 899.573 us; speedup vs baseline: 1.0813x; 1.0813x over previous
//
#include <hip/hip_runtime.h>
#include <stdint.h>

#define NN 50000
#define QWORDS 25600000   // N*F words; q_out region. mu_out region starts here.

typedef __attribute__((ext_vector_type(8))) short bf16x8;
typedef __attribute__((ext_vector_type(4))) float f32x4;

__device__ __forceinline__ uint32_t f2bf(float x){
  uint32_t u = __builtin_bit_cast(uint32_t, x);
  u += 0x7FFFu + ((u >> 16) & 1u);          // RNE
  return u >> 16;
}
__device__ __forceinline__ float bf2f(uint32_t b){
  uint32_t u = b << 16;
  return __builtin_bit_cast(float, u);
}
__device__ __forceinline__ void gload16(const uint16_t* g, uint16_t* l){
  __builtin_amdgcn_global_load_lds(
      (const __attribute__((address_space(1))) uint32_t*)g,
      (__attribute__((address_space(3))) uint32_t*)l, 16, 0, 0);
}
__device__ __forceinline__ f32x4 mfma16(bf16x8 a, bf16x8 b, f32x4 c){
  return __builtin_amdgcn_mfma_f32_16x16x32_bf16(a, b, c, 0, 0, 0);
}

#define FENCE() asm volatile("" ::: "memory")

// ---------------- K0: weights f32 -> bf16 into ws ----------------
// layout (u16): [0,524288) W_mix | [524288,1048576) W1 | [1048576,1835008) W2
// optional [1835008, +76800000) muW bf16 (if ws large enough)
__global__ void k_convert(const float* __restrict__ wmix, const float* __restrict__ w1,
                          const float* __restrict__ w2, uint16_t* __restrict__ dst){
  int i = blockIdx.x * 256 + threadIdx.x;   // float4 index; grid covers exactly 458752
  int e = i << 2;
  const float* s; int o;
  if (e < 524288)       { s = wmix; o = e; }
  else if (e < 1048576) { s = w1;   o = e - 524288; }
  else                  { s = w2;   o = e - 1048576; }
  f32x4 v = *(const f32x4*)(s + o);
  uint2 pk;
  pk.x = f2bf(v[0]) | (f2bf(v[1]) << 16);
  pk.y = f2bf(v[2]) | (f2bf(v[3]) << 16);
  *(uint2*)(dst + e) = pk;
}

// ---------------- K1 (fallback, f32 muW) -------------------------------------
__global__ __launch_bounds__(512, 4)
void k_gemm1(const float* __restrict__ mu, const uint16_t* __restrict__ wmixb,
             uint16_t* __restrict__ qh, float* __restrict__ muW){
  __shared__ uint16_t As[2][12288];   // 192x64 (r = d*64+nrow), 2x24KB
  __shared__ uint16_t Bs[2][8192];    // 128x64, 2x16KB
  const int tid  = threadIdx.x;
  const int lane = tid & 63;
  const int w    = tid >> 6;          // 0..7
  const int wn   = w & 3;             // n-quarter (16 rows)
  const int wf   = w >> 2;            // f-half (2 col-pairs)
  const int orig = blockIdx.x;
  const int j    = (orig & 7) * 782 + (orig >> 3);   // bijective XCD chunking
  const int f0   = (j & 7) * 64;
  const int n0   = (j >> 3) * 64;
  const int lrow = tid >> 4;          // 0..31
  const int lcol = (tid & 15) * 4;    // f32/u16 col base

  f32x4 ar[6];
  auto A_LOAD = [&](int ks){
    const int k0 = ks * 64;
    #pragma unroll
    for (int p=0; p<6; ++p){
      int r = p*32 + lrow;            // 0..191 = d*64 + nrow
      int d = r >> 6, nrow = r & 63;
      int n = n0 + nrow;
      int g = (n < NN ? n : NN-1)*3 + d;
      ar[p] = *(const f32x4*)(mu + (size_t)g*512 + k0 + lcol);
    }
  };
  auto A_WRITE = [&](int buf){
    #pragma unroll
    for (int p=0; p<6; ++p){
      int r = p*32 + lrow;
      f32x4 v = ar[p];
      uint2 pk;
      pk.x = f2bf(v[0]) | (f2bf(v[1]) << 16);
      pk.y = f2bf(v[2]) | (f2bf(v[3]) << 16);
      *(uint2*)&As[buf][r*64 + (lcol ^ ((r&7)<<3))] = pk;
    }
  };
  auto B_ISSUE = [&](int ks, int buf){
    const int k0 = ks * 64;
    #pragma unroll
    for (int jj=0; jj<2; ++jj){
      int jb = w*2 + jj;                 // 0..15
      int row = jb*8 + (lane>>3);
      int g = (row < 64) ? (f0 + row) : (448 + f0 + row);
      int srcc = ((lane&7) ^ ((lane>>3)&7)) * 8;
      gload16(wmixb + (size_t)g*512 + k0 + srcc, &Bs[buf][jb*512]);
    }
  };

  const f32x4 z4 = {0.f,0.f,0.f,0.f};
  f32x4 acc[3][4];
  #pragma unroll
  for (int d=0; d<3; ++d)
    #pragma unroll
    for (int nt=0; nt<4; ++nt) acc[d][nt] = z4;

  A_LOAD(0); B_ISSUE(0, 0); A_WRITE(0);
  for (int ks=0; ks<8; ++ks){
    const int cur = ks & 1;
    __syncthreads();
    if (ks < 7){ A_LOAD(ks+1); B_ISSUE(ks+1, cur^1); }
    #pragma unroll
    for (int kf=0; kf<2; ++kf){
      int kc = kf*32 + (lane>>4)*8;
      bf16x8 af[3];
      #pragma unroll
      for (int d=0; d<3; ++d){
        int r = d*64 + wn*16 + (lane&15);
        af[d] = *(const bf16x8*)&As[cur][r*64 + (kc ^ ((r&7)<<3))];
      }
      #pragma unroll
      for (int nt=0; nt<4; ++nt){
        int ntg = wf*2 + (nt&1) + (nt>>1)*4;
        int rr = ntg*16 + (lane&15);
        bf16x8 bf = *(const bf16x8*)&Bs[cur][rr*64 + (kc ^ ((rr&7)<<3))];
        #pragma unroll
        for (int d=0; d<3; ++d)
          acc[d][nt] = mfma16(bf, af[d], acc[d][nt]);   // SWAPPED: D[f, n]
      }
    }
    if (ks < 7) A_WRITE(cur^1);
  }

  const int rb4 = (lane >> 4) * 4;
  const int nthr = n0 + wn*16 + (lane & 15);
  if (nthr < NN){
    #pragma unroll
    for (int c=0; c<2; ++c){
      int f = f0 + (wf*2 + c)*16 + rb4;
      uint2 pkv, pkd; f32x4 u0v, u1v, u2v;
      uint32_t vb[4], db[4];
      #pragma unroll
      for (int p=0; p<4; ++p){
        float v0 = acc[0][c][p],   v1 = acc[1][c][p],   v2 = acc[2][c][p];
        float u0 = acc[0][c+2][p], u1 = acc[1][c+2][p], u2 = acc[2][c+2][p];
        float vn = sqrtf(v0*v0 + v1*v1 + v2*v2 + 1e-8f);
        float dt = v0*u0 + v1*u1 + v2*u2;
        vb[p] = f2bf(vn); db[p] = f2bf(dt);
        u0v[p] = u0; u1v[p] = u1; u2v[p] = u2;
      }
      pkv.x = vb[0] | (vb[1] << 16); pkv.y = vb[2] | (vb[3] << 16);
      pkd.x = db[0] | (db[1] << 16); pkd.y = db[2] | (db[3] << 16);
      *(uint2*)(qh + (size_t)nthr*1024 + f)       = pkv;
      *(uint2*)(qh + (size_t)nthr*1024 + 512 + f) = pkd;
      size_t mb = (size_t)nthr*1536 + f;
      *(f32x4*)(muW + mb)        = u0v;
      *(f32x4*)(muW + mb + 512)  = u1v;
      *(f32x4*)(muW + mb + 1024) = u2v;
    }
  }
}

// ---------------- K1b (round-10 proven): muW stored bf16 in ws ---------------
__global__ __launch_bounds__(512, 4)
void k_gemm1b(const float* __restrict__ mu, const uint16_t* __restrict__ wmixb,
              uint16_t* __restrict__ qh, uint16_t* __restrict__ mw16){
  __shared__ uint16_t As[2][12288];
  __shared__ uint16_t Bs[2][8192];
  const int tid  = threadIdx.x;
  const int lane = tid & 63;
  const int w    = tid >> 6;
  const int wn   = w & 3;
  const int wf   = w >> 2;
  const int orig = blockIdx.x;
  const int j    = (orig & 7) * 782 + (orig >> 3);
  const int f0   = (j & 7) * 64;
  const int n0   = (j >> 3) * 64;
  const int lrow = tid >> 4;
  const int lcol = (tid & 15) * 4;

  f32x4 ar[6];
  auto A_LOAD = [&](int ks){
    const int k0 = ks * 64;
    #pragma unroll
    for (int p=0; p<6; ++p){
      int r = p*32 + lrow;
      int d = r >> 6, nrow = r & 63;
      int n = n0 + nrow;
      int g = (n < NN ? n : NN-1)*3 + d;
      ar[p] = *(const f32x4*)(mu + (size_t)g*512 + k0 + lcol);
    }
  };
  auto A_WRITE = [&](int buf){
    #pragma unroll
    for (int p=0; p<6; ++p){
      int r = p*32 + lrow;
      f32x4 v = ar[p];
      uint2 pk;
      pk.x = f2bf(v[0]) | (f2bf(v[1]) << 16);
      pk.y = f2bf(v[2]) | (f2bf(v[3]) << 16);
      *(uint2*)&As[buf][r*64 + (lcol ^ ((r&7)<<3))] = pk;
    }
  };
  auto B_ISSUE = [&](int ks, int buf){
    const int k0 = ks * 64;
    #pragma unroll
    for (int jj=0; jj<2; ++jj){
      int jb = w*2 + jj;
      int row = jb*8 + (lane>>3);
      int g = (row < 64) ? (f0 + row) : (448 + f0 + row);
      int srcc = ((lane&7) ^ ((lane>>3)&7)) * 8;
      gload16(wmixb + (size_t)g*512 + k0 + srcc, &Bs[buf][jb*512]);
    }
  };

  const f32x4 z4 = {0.f,0.f,0.f,0.f};
  f32x4 acc[3][4];
  #pragma unroll
  for (int d=0; d<3; ++d)
    #pragma unroll
    for (int nt=0; nt<4; ++nt) acc[d][nt] = z4;

  A_LOAD(0); B_ISSUE(0, 0); A_WRITE(0);
  for (int ks=0; ks<8; ++ks){
    const int cur = ks & 1;
    __syncthreads();
    if (ks < 7){ A_LOAD(ks+1); B_ISSUE(ks+1, cur^1); }
    #pragma unroll
    for (int kf=0; kf<2; ++kf){
      int kc = kf*32 + (lane>>4)*8;
      bf16x8 af[3];
      #pragma unroll
      for (int d=0; d<3; ++d){
        int r = d*64 + wn*16 + (lane&15);
        af[d] = *(const bf16x8*)&As[cur][r*64 + (kc ^ ((r&7)<<3))];
      }
      #pragma unroll
      for (int nt=0; nt<4; ++nt){
        int ntg = wf*2 + (nt&1) + (nt>>1)*4;
        int rr = ntg*16 + (lane&15);
        bf16x8 bf = *(const bf16x8*)&Bs[cur][rr*64 + (kc ^ ((rr&7)<<3))];
        #pragma unroll
        for (int d=0; d<3; ++d)
          acc[d][nt] = mfma16(bf, af[d], acc[d][nt]);
      }
    }
    if (ks < 7) A_WRITE(cur^1);
  }

  const int rb4 = (lane >> 4) * 4;
  const int nthr = n0 + wn*16 + (lane & 15);
  if (nthr < NN){
    #pragma unroll
    for (int c=0; c<2; ++c){
      int f = f0 + (wf*2 + c)*16 + rb4;
      uint2 pkv, pkd, pw0, pw1, pw2;
      uint32_t vb[4], db[4], w0[4], w1[4], w2[4];
      #pragma unroll
      for (int p=0; p<4; ++p){
        float v0 = acc[0][c][p],   v1 = acc[1][c][p],   v2 = acc[2][c][p];
        float u0 = acc[0][c+2][p], u1 = acc[1][c+2][p], u2 = acc[2][c+2][p];
        float vn = sqrtf(v0*v0 + v1*v1 + v2*v2 + 1e-8f);
        float dt = v0*u0 + v1*u1 + v2*u2;
        vb[p] = f2bf(vn); db[p] = f2bf(dt);
        w0[p] = f2bf(u0); w1[p] = f2bf(u1); w2[p] = f2bf(u2);
      }
      pkv.x = vb[0] | (vb[1] << 16); pkv.y = vb[2] | (vb[3] << 16);
      pkd.x = db[0] | (db[1] << 16); pkd.y = db[2] | (db[3] << 16);
      pw0.x = w0[0] | (w0[1] << 16); pw0.y = w0[2] | (w0[3] << 16);
      pw1.x = w1[0] | (w1[1] << 16); pw1.y = w1[2] | (w1[3] << 16);
      pw2.x = w2[0] | (w2[1] << 16); pw2.y = w2[2] | (w2[3] << 16);
      *(uint2*)(qh + (size_t)nthr*1024 + f)       = pkv;
      *(uint2*)(qh + (size_t)nthr*1024 + 512 + f) = pkd;
      size_t mb = (size_t)nthr*1536 + f;
      *(uint2*)(mw16 + mb)        = pw0;
      *(uint2*)(mw16 + mb + 512)  = pw1;
      *(uint2*)(mw16 + mb + 1024) = pw2;
    }
  }
}

// ---------------- K2 v2 (round-7 proven): 512 threads ------------------------
__global__ __launch_bounds__(512, 4)
void k_gemm2(const float* __restrict__ q, const uint16_t* __restrict__ w1b,
             const float* __restrict__ b1, uint16_t* __restrict__ qh){
  __shared__ uint16_t A2[2][2048];    // 64x32, 2x4KB
  __shared__ uint16_t B2[2][16384];   // 512x32, 2x32KB
  const int tid  = threadIdx.x;
  const int lane = tid & 63;
  const int w    = tid >> 6;          // 0..7
  const int wm   = w >> 2;            // 0..1 (32-row half)
  const int wn   = w & 3;             // 0..3 (128-col quarter)
  const int n0   = blockIdx.x * 64;

  f32x4 qa;
  auto QA_LOAD = [&](int s){
    int k0 = s*32;
    int row = tid >> 3, ch = tid & 7;
    int nc = (n0 + row < NN) ? n0 + row : NN-1;
    qa = *(const f32x4*)(q + (size_t)nc*512 + k0 + ch*4);
  };
  auto QA_WRITE = [&](int buf){
    int row = tid >> 3, ch = tid & 7;
    uint2 pk;
    pk.x = f2bf(qa[0]) | (f2bf(qa[1]) << 16);
    pk.y = f2bf(qa[2]) | (f2bf(qa[3]) << 16);
    *(uint2*)&A2[buf][row*32 + (((ch>>1) ^ (row&3))<<3) + (ch&1)*4] = pk;
  };
  auto VA_ISSUE = [&](int s, int buf){
    if (w < 4){
      int k0v = (s-16)*32;
      int row = w*16 + (lane>>2);
      int nc = (n0 + row < NN) ? n0 + row : NN-1;
      int srcch = (lane&3) ^ (row&3);
      gload16(qh + (size_t)nc*1024 + k0v + srcch*8, &A2[buf][w*512]);
    }
  };
  auto B_ISSUE = [&](int s, int buf){
    int k0 = s*32;
    #pragma unroll
    for (int jj=0; jj<4; ++jj){
      int j = w*4 + jj;
      int row = j*16 + (lane>>2);
      int srcch = (lane&3) ^ (row&3);
      gload16(w1b + (size_t)row*1024 + k0 + srcch*8, &B2[buf][j*512]);
    }
  };

  const f32x4 z4 = {0.f,0.f,0.f,0.f};
  f32x4 acc2[2][8];
  #pragma unroll
  for (int mt=0; mt<2; ++mt)
    #pragma unroll
    for (int nt=0; nt<8; ++nt) acc2[mt][nt] = z4;

  QA_LOAD(0); B_ISSUE(0, 0); QA_WRITE(0);
  for (int s=0; s<32; ++s){
    const int cur = s & 1;
    __syncthreads();
    if (s < 31){
      if (s+1 < 16) QA_LOAD(s+1); else VA_ISSUE(s+1, cur^1);
      B_ISSUE(s+1, cur^1);
    }
    {
      int kc = (lane>>4)*8;
      bf16x8 a[2];
      #pragma unroll
      for (int mt=0; mt<2; ++mt){
        int r = wm*32 + mt*16 + (lane&15);
        a[mt] = *(const bf16x8*)&A2[cur][r*32 + (kc ^ ((r&3)<<3))];
      }
      #pragma unroll
      for (int nt=0; nt<8; ++nt){
        int rr = wn*128 + nt*16 + (lane&15);
        bf16x8 b = *(const bf16x8*)&B2[cur][rr*32 + (kc ^ ((rr&3)<<3))];
        acc2[0][nt] = mfma16(a[0], b, acc2[0][nt]);
        acc2[1][nt] = mfma16(a[1], b, acc2[1][nt]);
      }
    }
    if (s < 31 && s+1 < 16) QA_WRITE(cur^1);
  }

  const int rb4 = (lane >> 4) * 4;
  #pragma unroll
  for (int nt=0; nt<8; ++nt){
    int col = wn*128 + nt*16 + (lane&15);
    float bb = b1[col];
    #pragma unroll
    for (int mt=0; mt<2; ++mt)
      #pragma unroll
      for (int j=0; j<4; ++j){
        int n = n0 + wm*32 + mt*16 + rb4 + j;
        if (n < NN){
          float x = acc2[mt][nt][j] + bb;
          float sv = x / (1.f + __expf(-x));
          qh[(size_t)n*1024 + col] = (uint16_t)f2bf(sv);
        }
      }
  }
}

// ---------------- K3 v10: wave-specialized producer/consumer -----------------
// vmcnt is per-wave and in-order: any wave that interleaves L2 B-loads with
// HBM stream loads must drain the streams on every B-wait (the v8 stall).
// Split: waves 4-7 = producers (ONLY B global_load_lds; pure-B queue, vmcnt(0)
// costs just L2 latency). Waves 0-3 = consumers (ds_read+MFMA, both wm halves,
// own E-streams issued p0-p2 and drained once at p7 after 5-7 phases = free).
// Consumers never vmcnt-wait on B: producer drain + barrier guarantees LDS.
// One barrier per phase; counts match (65/wave). dt-clobber ordering identical
// to v8 (phases are barrier-ordered block-wide). grid = 1563, 80KB LDS.
__global__ __launch_bounds__(512, 4)
void k_gemm3d(const float* __restrict__ q, const float* __restrict__ mu,
              const uint16_t* __restrict__ w2b, const float* __restrict__ b2,
              float* __restrict__ dout, const uint16_t* __restrict__ mw16){
  __shared__ uint16_t Hs[32*512];     // 32KB
  __shared__ uint16_t B3[2][12288];   // 2x24KB ring
  const int tid  = threadIdx.x;
  const int lane = tid & 63;
  const int w    = tid >> 6;          // 0..7
  const int n0   = blockIdx.x * 32;
  const uint16_t* qh = (const uint16_t*)dout;
  float* mout = dout + (size_t)QWORDS;
  const int l15 = lane & 15;
  const int rb4 = (lane >> 4) * 4;

  // prologue: Hs staging by all 8 waves (4 rows each)
  #pragma unroll
  for (int i=0; i<4; ++i){
    int row = w*4 + i;
    int nc2 = (n0 + row < NN) ? n0 + row : NN-1;
    gload16(qh + (size_t)nc2*1024 + (size_t)((lane ^ (row&7))*8), &Hs[row*512]);
  }

  if (w >= 4){
    // ======================= producer waves =======================
    const int pw = w - 4;             // 0..3
    auto B_ISSUE = [&](int it, int ks){
      uint16_t* slot = B3[ks & 1];
      #pragma unroll
      for (int jj=0; jj<6; ++jj){
        int jx = pw*6 + jj;           // 0..23
        int rr = jx*8 + (lane>>3);    // 0..191
        int s3 = rr >> 6, fi = rr & 63;
        int g = s3*512 + it*64 + fi;
        gload16(w2b + (size_t)g*512 + ks*64 + ((lane&7) ^ (rr&7))*8, slot + jx*512);
      }
    };
    B_ISSUE(0, 0);
    asm volatile("s_waitcnt vmcnt(0)" ::: "memory");
    __syncthreads();
    #pragma unroll 1
    for (int it=0; it<8; ++it){
      #pragma unroll
      for (int p=0; p<8; ++p){
        int nit = it, nks = p+1;
        if (nks == 8){ nks = 0; nit = it+1; }
        if (nit < 8) B_ISSUE(nit, nks);
        asm volatile("s_waitcnt vmcnt(0)" ::: "memory");
        __builtin_amdgcn_s_barrier();
      }
    }
  } else {
    // ======================= consumer waves =======================
    const int cw = w;                 // 0..3 f-group
    asm volatile("s_waitcnt vmcnt(0)" ::: "memory");
    __syncthreads();
    const int nth0 = n0 + l15, nth1 = n0 + 16 + l15;
    const int nc0 = nth0 < NN ? nth0 : NN-1;
    const int nc1 = nth1 < NN ? nth1 : NN-1;
    const f32x4 z4 = {0.f,0.f,0.f,0.f};
    f32x4 acc3[2][3];
    f32x4 qv0, qv1, bbv[3], muv0[3], muv1[3];
    uint2 du0, du1, mwu0[3], mwu1[3];
    int fb = 0;

#define K3D_MFMA(KS) do{ \
    const uint16_t* bsl = B3[(KS)&1]; \
    __builtin_amdgcn_s_setprio(1); \
    _Pragma("unroll") \
    for (int kf=0; kf<2; ++kf){ \
      int ch = ((KS)*8 + kf*4 + (lane>>4)) ^ (l15&7); \
      bf16x8 a0 = *(const bf16x8*)&Hs[l15*512 + ch*8]; \
      bf16x8 a1 = *(const bf16x8*)&Hs[(16+l15)*512 + ch*8]; \
      _Pragma("unroll") \
      for (int s3=0; s3<3; ++s3){ \
        int rr = s3*64 + cw*16 + l15; \
        int chb = (kf*4 + (lane>>4)) ^ (rr&7); \
        bf16x8 b = *(const bf16x8*)&bsl[rr*64 + chb*8]; \
        acc3[0][s3] = mfma16(b, a0, acc3[0][s3]); \
        acc3[1][s3] = mfma16(b, a1, acc3[1][s3]); \
      } \
    } \
    __builtin_amdgcn_s_setprio(0); \
  } while(0)

    #pragma unroll 1
    for (int it=0; it<8; ++it){
      // ---- p0: E0 (bb, dt, q) ----
      #pragma unroll
      for (int m=0; m<2; ++m)
        #pragma unroll
        for (int s3=0; s3<3; ++s3) acc3[m][s3] = z4;
      fb = it*64 + cw*16 + rb4;
      bbv[0] = *(const f32x4*)(b2 + fb);
      bbv[1] = *(const f32x4*)(b2 + 512 + fb);
      bbv[2] = *(const f32x4*)(b2 + 1024 + fb);
      du0 = *(const uint2*)(qh + (size_t)nc0*1024 + 512 + fb);
      du1 = *(const uint2*)(qh + (size_t)nc1*1024 + 512 + fb);
      qv0 = *(const f32x4*)(q + (size_t)nc0*512 + fb);
      qv1 = *(const f32x4*)(q + (size_t)nc1*512 + fb);
      FENCE();
      K3D_MFMA(0);
      __builtin_amdgcn_s_barrier();

      // ---- p1: E1 (mu) ----
      {
        size_t mb0 = (size_t)nc0*1536 + fb, mb1 = (size_t)nc1*1536 + fb;
        muv0[0] = *(const f32x4*)(mu + mb0);
        muv0[1] = *(const f32x4*)(mu + mb0 + 512);
        muv0[2] = *(const f32x4*)(mu + mb0 + 1024);
        muv1[0] = *(const f32x4*)(mu + mb1);
        muv1[1] = *(const f32x4*)(mu + mb1 + 512);
        muv1[2] = *(const f32x4*)(mu + mb1 + 1024);
      }
      FENCE();
      K3D_MFMA(1);
      __builtin_amdgcn_s_barrier();

      // ---- p2: E2 (mw bf16) ----
      {
        size_t mb0 = (size_t)nc0*1536 + fb, mb1 = (size_t)nc1*1536 + fb;
        mwu0[0] = *(const uint2*)(mw16 + mb0);
        mwu0[1] = *(const uint2*)(mw16 + mb0 + 512);
        mwu0[2] = *(const uint2*)(mw16 + mb0 + 1024);
        mwu1[0] = *(const uint2*)(mw16 + mb1);
        mwu1[1] = *(const uint2*)(mw16 + mb1 + 512);
        mwu1[2] = *(const uint2*)(mw16 + mb1 + 1024);
      }
      FENCE();
      K3D_MFMA(2);
      __builtin_amdgcn_s_barrier();

      // ---- p3..p6 ----
      K3D_MFMA(3); __builtin_amdgcn_s_barrier();
      K3D_MFMA(4); __builtin_amdgcn_s_barrier();
      K3D_MFMA(5); __builtin_amdgcn_s_barrier();
      K3D_MFMA(6); __builtin_amdgcn_s_barrier();

      // ---- p7: MFMA + drain own E + epilogue ----
      K3D_MFMA(7);
      asm volatile("s_waitcnt vmcnt(0)" ::: "memory");
      {
        auto dec = [&](uint2 u, int p)->float{
          uint32_t h = (p & 2) ? u.y : u.x;
          return bf2f((p & 1) ? (h >> 16) : (h & 0xffffu));
        };
        if (nth0 < NN){
          f32x4 qo, mo0, mo1, mo2;
          #pragma unroll
          for (int p=0; p<4; ++p){
            float x0 = acc3[0][0][p] + bbv[0][p];
            float x1 = acc3[0][1][p] + bbv[1][p];
            float x2 = acc3[0][2][p] + bbv[2][p];
            qo[p]  = qv0[p] + x0 + x2*dec(du0, p);
            mo0[p] = muv0[0][p] + x1*dec(mwu0[0], p);
            mo1[p] = muv0[1][p] + x1*dec(mwu0[1], p);
            mo2[p] = muv0[2][p] + x1*dec(mwu0[2], p);
          }
          *(f32x4*)(dout + (size_t)nth0*512 + fb) = qo;
          size_t mb = (size_t)nth0*1536 + fb;
          *(f32x4*)(mout + mb)        = mo0;
          *(f32x4*)(mout + mb + 512)  = mo1;
          *(f32x4*)(mout + mb + 1024) = mo2;
        }
        if (nth1 < NN){
          f32x4 qo, mo0, mo1, mo2;
          #pragma unroll
          for (int p=0; p<4; ++p){
            float x0 = acc3[1][0][p] + bbv[0][p];
            float x1 = acc3[1][1][p] + bbv[1][p];
            float x2 = acc3[1][2][p] + bbv[2][p];
            qo[p]  = qv1[p] + x0 + x2*dec(du1, p);
            mo0[p] = muv1[0][p] + x1*dec(mwu1[0], p);
            mo1[p] = muv1[1][p] + x1*dec(mwu1[1], p);
            mo2[p] = muv1[2][p] + x1*dec(mwu1[2], p);
          }
          *(f32x4*)(dout + (size_t)nth1*512 + fb) = qo;
          size_t mb = (size_t)nth1*1536 + fb;
          *(f32x4*)(mout + mb)        = mo0;
          *(f32x4*)(mout + mb + 512)  = mo1;
          *(f32x4*)(mout + mb + 1024) = mo2;
        }
      }
      __builtin_amdgcn_s_barrier();
    }
#undef K3D_MFMA
  }
}

// ---------------- K3 (fallback, round-8): f32 muW in-place -------------------
__global__ __launch_bounds__(512, 4)
void k_gemm3(const float* __restrict__ q, const float* __restrict__ mu,
             const uint16_t* __restrict__ w2b, const float* __restrict__ b2,
             float* __restrict__ dout){
  __shared__ uint16_t Hs[32*512];     // 32KB
  __shared__ uint16_t B3[2][12288];   // 2x24KB ring
  const int tid  = threadIdx.x;
  const int lane = tid & 63;
  const int w    = tid >> 6;
  const int wm   = w >> 2;
  const int wn   = w & 3;
  const int n0   = blockIdx.x * 32;
  const uint16_t* qh = (const uint16_t*)dout;
  float* mout = dout + (size_t)QWORDS;
  const int l15 = lane & 15;
  const int rb4 = (lane >> 4) * 4;
  const f32x4 z4 = {0.f,0.f,0.f,0.f};

  #pragma unroll
  for (int i=0; i<4; ++i){
    int row = w*4 + i;
    int nc2 = (n0 + row < NN) ? n0 + row : NN-1;
    gload16(qh + (size_t)nc2*1024 + (size_t)((lane ^ (row&7))*8), &Hs[row*512]);
  }

  auto B_ISSUE = [&](int it, int ks, uint16_t* slot){
    #pragma unroll
    for (int jj=0; jj<3; ++jj){
      int jx = w*3 + jj;
      int rr = jx*8 + (lane>>3);
      int s3 = rr >> 6, fi = rr & 63;
      int g = s3*512 + it*64 + fi;
      gload16(w2b + (size_t)g*512 + ks*64 + ((lane&7) ^ (rr&7))*8, slot + jx*512);
    }
  };
  B_ISSUE(0, 0, B3[0]);

  const int nthr = n0 + wm*16 + l15;
  const int nc   = nthr < NN ? nthr : NN-1;

  f32x4 qv, bbv[3], muv[3], mwv[3];
  float dtv[4];
  int   fb = 0;
  f32x4 acc3[3];

#define K3_MFMA(KS) do{ \
    const uint16_t* bsl = B3[(KS)&1]; \
    __builtin_amdgcn_s_setprio(1); \
    _Pragma("unroll") \
    for (int kf=0; kf<2; ++kf){ \
      int r = wm*16 + l15; \
      int ch = ((KS)*8 + kf*4 + (lane>>4)) ^ (r&7); \
      bf16x8 a = *(const bf16x8*)&Hs[r*512 + ch*8]; \
      _Pragma("unroll") \
      for (int s3=0; s3<3; ++s3){ \
        int rr = s3*64 + wn*16 + l15; \
        int chb = (kf*4 + (lane>>4)) ^ (rr&7); \
        bf16x8 b = *(const bf16x8*)&bsl[rr*64 + chb*8]; \
        acc3[s3] = mfma16(b, a, acc3[s3]); \
      } \
    } \
    __builtin_amdgcn_s_setprio(0); \
  } while(0)

  #pragma unroll 1
  for (int it=0; it<8; ++it){
    if (it) { asm volatile("s_waitcnt vmcnt(4)" ::: "memory"); }
    else    { asm volatile("s_waitcnt vmcnt(0)" ::: "memory"); }
    __builtin_amdgcn_s_barrier();
    B_ISSUE(it, 1, B3[1]);
    FENCE();
    {
      #pragma unroll
      for (int s3=0; s3<3; ++s3) acc3[s3] = z4;
      fb = it*64 + wn*16 + rb4;
      bbv[0] = *(const f32x4*)(b2 + fb);
      bbv[1] = *(const f32x4*)(b2 + 512 + fb);
      bbv[2] = *(const f32x4*)(b2 + 1024 + fb);
      uint2 du = *(const uint2*)(qh + (size_t)nc*1024 + 512 + fb);
      dtv[0] = bf2f(du.x & 0xffff); dtv[1] = bf2f(du.x >> 16);
      dtv[2] = bf2f(du.y & 0xffff); dtv[3] = bf2f(du.y >> 16);
      qv = *(const f32x4*)(q + (size_t)nc*512 + fb);
    }
    FENCE();
    K3_MFMA(0);

    asm volatile("s_waitcnt vmcnt(5)" ::: "memory");
    __builtin_amdgcn_s_barrier();
    B_ISSUE(it, 2, B3[0]);
    FENCE();
    {
      size_t mb = (size_t)nc*1536 + fb;
      muv[0] = *(const f32x4*)(mu + mb);
      muv[1] = *(const f32x4*)(mu + mb + 512);
      muv[2] = *(const f32x4*)(mu + mb + 1024);
    }
    FENCE();
    K3_MFMA(1);

    asm volatile("s_waitcnt vmcnt(3)" ::: "memory");
    __builtin_amdgcn_s_barrier();
    B_ISSUE(it, 3, B3[1]);
    FENCE();
    {
      size_t mb = (size_t)nc*1536 + fb;
      mwv[0] = *(const f32x4*)(mout + mb);
      mwv[1] = *(const f32x4*)(mout + mb + 512);
      mwv[2] = *(const f32x4*)(mout + mb + 1024);
    }
    FENCE();
    K3_MFMA(2);

    asm volatile("s_waitcnt vmcnt(3)" ::: "memory");
    __builtin_amdgcn_s_barrier();
    B_ISSUE(it, 4, B3[0]);
    FENCE();
    K3_MFMA(3);

    asm volatile("s_waitcnt vmcnt(0)" ::: "memory");
    __builtin_amdgcn_s_barrier();
    B_ISSUE(it, 5, B3[1]);
    FENCE();
    K3_MFMA(4);

    asm volatile("s_waitcnt vmcnt(0)" ::: "memory");
    __builtin_amdgcn_s_barrier();
    B_ISSUE(it, 6, B3[0]);
    FENCE();
    K3_MFMA(5);

    asm volatile("s_waitcnt vmcnt(0)" ::: "memory");
    __builtin_amdgcn_s_barrier();
    B_ISSUE(it, 7, B3[1]);
    FENCE();
    K3_MFMA(6);

    asm volatile("s_waitcnt vmcnt(0)" ::: "memory");
    __builtin_amdgcn_s_barrier();
    if (it < 7) B_ISSUE(it+1, 0, B3[0]);
    FENCE();
    K3_MFMA(7);
    if (nthr < NN){
      f32x4 qo, m0, m1, m2;
      #pragma unroll
      for (int p=0; p<4; ++p){
        float x0 = acc3[0][p] + bbv[0][p];
        float x1 = acc3[1][p] + bbv[1][p];
        float x2 = acc3[2][p] + bbv[2][p];
        qo[p] = qv[p] + x0 + x2*dtv[p];
        m0[p] = muv[0][p] + x1*mwv[0][p];
        m1[p] = muv[1][p] + x1*mwv[1][p];
        m2[p] = muv[2][p] + x1*mwv[2][p];
      }
      *(f32x4*)(dout + (size_t)nthr*512 + fb) = qo;
      size_t mb = (size_t)nthr*1536 + fb;
      *(f32x4*)(mout + mb)        = m0;
      *(f32x4*)(mout + mb + 512)  = m1;
      *(f32x4*)(mout + mb + 1024) = m2;
    }
  }
#undef K3_MFMA
}

extern "C" void kernel_launch(void* const* d_in, const int* in_sizes, int n_in,
                              void* d_out, int out_size, void* d_ws, size_t ws_size,
                              hipStream_t stream){
  (void)in_sizes; (void)n_in; (void)out_size;
  const float* q    = (const float*)d_in[0];
  const float* mu   = (const float*)d_in[1];
  const float* wmix = (const float*)d_in[2];
  const float* w1   = (const float*)d_in[3];
  const float* b1   = (const float*)d_in[4];
  const float* w2   = (const float*)d_in[5];
  const float* b2   = (const float*)d_in[6];
  uint16_t* wb = (uint16_t*)d_ws;
  float* dout = (float*)d_out;

  hipLaunchKernelGGL(k_convert, dim3(1792), dim3(256), 0, stream, wmix, w1, w2, wb);

  const size_t need = ((size_t)1835008 + (size_t)NN*1536) * 2;   // 157.3 MB
  if (ws_size >= need){
    uint16_t* mw16 = wb + 1835008;
    hipLaunchKernelGGL(k_gemm1b, dim3(6256), dim3(512), 0, stream,
                       mu, wb, (uint16_t*)d_out, mw16);
    hipLaunchKernelGGL(k_gemm2, dim3(782), dim3(512), 0, stream,
                       q, wb + 524288, b1, (uint16_t*)d_out);
    hipLaunchKernelGGL(k_gemm3d, dim3(1563), dim3(512), 0, stream,
                       q, mu, wb + 1048576, b2, dout, mw16);
  } else {
    hipLaunchKernelGGL(k_gemm1, dim3(6256), dim3(512), 0, stream,
                       mu, wb, (uint16_t*)d_out, dout + (size_t)QWORDS);
    hipLaunchKernelGGL(k_gemm2, dim3(782), dim3(512), 0, stream,
                       q, wb + 524288, b1, (uint16_t*)d_out);
    hipLaunchKernelGGL(k_gemm3, dim3(1563), dim3(512), 0, stream,
                       q, mu, wb + 1048576, b2, dout);
  }
}

// Round 13
// 842.832 us; speedup vs baseline: 1.1541x; 1.0673x over previous
//
#include <hip/hip_runtime.h>
#include <stdint.h>

#define NN 50000
#define QWORDS 25600000   // N*F words; q_out region. mu_out region starts here.

typedef __attribute__((ext_vector_type(8))) short bf16x8;
typedef __attribute__((ext_vector_type(4))) float f32x4;

__device__ __forceinline__ uint32_t f2bf(float x){
  uint32_t u = __builtin_bit_cast(uint32_t, x);
  u += 0x7FFFu + ((u >> 16) & 1u);          // RNE
  return u >> 16;
}
__device__ __forceinline__ float bf2f(uint32_t b){
  uint32_t u = b << 16;
  return __builtin_bit_cast(float, u);
}
__device__ __forceinline__ void gload16(const uint16_t* g, uint16_t* l){
  __builtin_amdgcn_global_load_lds(
      (const __attribute__((address_space(1))) uint32_t*)g,
      (__attribute__((address_space(3))) uint32_t*)l, 16, 0, 0);
}
__device__ __forceinline__ f32x4 mfma16(bf16x8 a, bf16x8 b, f32x4 c){
  return __builtin_amdgcn_mfma_f32_16x16x32_bf16(a, b, c, 0, 0, 0);
}

#define FENCE() asm volatile("" ::: "memory")

// ---------------- K0: weights f32 -> bf16 into ws ----------------
// layout (u16): [0,524288) W_mix | [524288,1048576) W1 | [1048576,1835008) W2
// optional [1835008, +76800000) muW bf16 (if ws large enough)
__global__ void k_convert(const float* __restrict__ wmix, const float* __restrict__ w1,
                          const float* __restrict__ w2, uint16_t* __restrict__ dst){
  int i = blockIdx.x * 256 + threadIdx.x;   // float4 index; grid covers exactly 458752
  int e = i << 2;
  const float* s; int o;
  if (e < 524288)       { s = wmix; o = e; }
  else if (e < 1048576) { s = w1;   o = e - 524288; }
  else                  { s = w2;   o = e - 1048576; }
  f32x4 v = *(const f32x4*)(s + o);
  uint2 pk;
  pk.x = f2bf(v[0]) | (f2bf(v[1]) << 16);
  pk.y = f2bf(v[2]) | (f2bf(v[3]) << 16);
  *(uint2*)(dst + e) = pk;
}

// ---------------- K1 (fallback, f32 muW) -------------------------------------
__global__ __launch_bounds__(512, 4)
void k_gemm1(const float* __restrict__ mu, const uint16_t* __restrict__ wmixb,
             uint16_t* __restrict__ qh, float* __restrict__ muW){
  __shared__ uint16_t As[2][12288];   // 192x64 (r = d*64+nrow), 2x24KB
  __shared__ uint16_t Bs[2][8192];    // 128x64, 2x16KB
  const int tid  = threadIdx.x;
  const int lane = tid & 63;
  const int w    = tid >> 6;          // 0..7
  const int wn   = w & 3;             // n-quarter (16 rows)
  const int wf   = w >> 2;            // f-half (2 col-pairs)
  const int orig = blockIdx.x;
  const int j    = (orig & 7) * 782 + (orig >> 3);   // bijective XCD chunking
  const int f0   = (j & 7) * 64;
  const int n0   = (j >> 3) * 64;
  const int lrow = tid >> 4;          // 0..31
  const int lcol = (tid & 15) * 4;    // f32/u16 col base

  f32x4 ar[6];
  auto A_LOAD = [&](int ks){
    const int k0 = ks * 64;
    #pragma unroll
    for (int p=0; p<6; ++p){
      int r = p*32 + lrow;            // 0..191 = d*64 + nrow
      int d = r >> 6, nrow = r & 63;
      int n = n0 + nrow;
      int g = (n < NN ? n : NN-1)*3 + d;
      ar[p] = *(const f32x4*)(mu + (size_t)g*512 + k0 + lcol);
    }
  };
  auto A_WRITE = [&](int buf){
    #pragma unroll
    for (int p=0; p<6; ++p){
      int r = p*32 + lrow;
      f32x4 v = ar[p];
      uint2 pk;
      pk.x = f2bf(v[0]) | (f2bf(v[1]) << 16);
      pk.y = f2bf(v[2]) | (f2bf(v[3]) << 16);
      *(uint2*)&As[buf][r*64 + (lcol ^ ((r&7)<<3))] = pk;
    }
  };
  auto B_ISSUE = [&](int ks, int buf){
    const int k0 = ks * 64;
    #pragma unroll
    for (int jj=0; jj<2; ++jj){
      int jb = w*2 + jj;                 // 0..15
      int row = jb*8 + (lane>>3);
      int g = (row < 64) ? (f0 + row) : (448 + f0 + row);
      int srcc = ((lane&7) ^ ((lane>>3)&7)) * 8;
      gload16(wmixb + (size_t)g*512 + k0 + srcc, &Bs[buf][jb*512]);
    }
  };

  const f32x4 z4 = {0.f,0.f,0.f,0.f};
  f32x4 acc[3][4];
  #pragma unroll
  for (int d=0; d<3; ++d)
    #pragma unroll
    for (int nt=0; nt<4; ++nt) acc[d][nt] = z4;

  A_LOAD(0); B_ISSUE(0, 0); A_WRITE(0);
  for (int ks=0; ks<8; ++ks){
    const int cur = ks & 1;
    __syncthreads();
    if (ks < 7){ A_LOAD(ks+1); B_ISSUE(ks+1, cur^1); }
    #pragma unroll
    for (int kf=0; kf<2; ++kf){
      int kc = kf*32 + (lane>>4)*8;
      bf16x8 af[3];
      #pragma unroll
      for (int d=0; d<3; ++d){
        int r = d*64 + wn*16 + (lane&15);
        af[d] = *(const bf16x8*)&As[cur][r*64 + (kc ^ ((r&7)<<3))];
      }
      #pragma unroll
      for (int nt=0; nt<4; ++nt){
        int ntg = wf*2 + (nt&1) + (nt>>1)*4;
        int rr = ntg*16 + (lane&15);
        bf16x8 bf = *(const bf16x8*)&Bs[cur][rr*64 + (kc ^ ((rr&7)<<3))];
        #pragma unroll
        for (int d=0; d<3; ++d)
          acc[d][nt] = mfma16(bf, af[d], acc[d][nt]);   // SWAPPED: D[f, n]
      }
    }
    if (ks < 7) A_WRITE(cur^1);
  }

  const int rb4 = (lane >> 4) * 4;
  const int nthr = n0 + wn*16 + (lane & 15);
  if (nthr < NN){
    #pragma unroll
    for (int c=0; c<2; ++c){
      int f = f0 + (wf*2 + c)*16 + rb4;
      uint2 pkv, pkd; f32x4 u0v, u1v, u2v;
      uint32_t vb[4], db[4];
      #pragma unroll
      for (int p=0; p<4; ++p){
        float v0 = acc[0][c][p],   v1 = acc[1][c][p],   v2 = acc[2][c][p];
        float u0 = acc[0][c+2][p], u1 = acc[1][c+2][p], u2 = acc[2][c+2][p];
        float vn = sqrtf(v0*v0 + v1*v1 + v2*v2 + 1e-8f);
        float dt = v0*u0 + v1*u1 + v2*u2;
        vb[p] = f2bf(vn); db[p] = f2bf(dt);
        u0v[p] = u0; u1v[p] = u1; u2v[p] = u2;
      }
      pkv.x = vb[0] | (vb[1] << 16); pkv.y = vb[2] | (vb[3] << 16);
      pkd.x = db[0] | (db[1] << 16); pkd.y = db[2] | (db[3] << 16);
      *(uint2*)(qh + (size_t)nthr*1024 + f)       = pkv;
      *(uint2*)(qh + (size_t)nthr*1024 + 512 + f) = pkd;
      size_t mb = (size_t)nthr*1536 + f;
      *(f32x4*)(muW + mb)        = u0v;
      *(f32x4*)(muW + mb + 512)  = u1v;
      *(f32x4*)(muW + mb + 1024) = u2v;
    }
  }
}

// ---------------- K1b (round-10 proven): muW stored bf16 in ws ---------------
__global__ __launch_bounds__(512, 4)
void k_gemm1b(const float* __restrict__ mu, const uint16_t* __restrict__ wmixb,
              uint16_t* __restrict__ qh, uint16_t* __restrict__ mw16){
  __shared__ uint16_t As[2][12288];
  __shared__ uint16_t Bs[2][8192];
  const int tid  = threadIdx.x;
  const int lane = tid & 63;
  const int w    = tid >> 6;
  const int wn   = w & 3;
  const int wf   = w >> 2;
  const int orig = blockIdx.x;
  const int j    = (orig & 7) * 782 + (orig >> 3);
  const int f0   = (j & 7) * 64;
  const int n0   = (j >> 3) * 64;
  const int lrow = tid >> 4;
  const int lcol = (tid & 15) * 4;

  f32x4 ar[6];
  auto A_LOAD = [&](int ks){
    const int k0 = ks * 64;
    #pragma unroll
    for (int p=0; p<6; ++p){
      int r = p*32 + lrow;
      int d = r >> 6, nrow = r & 63;
      int n = n0 + nrow;
      int g = (n < NN ? n : NN-1)*3 + d;
      ar[p] = *(const f32x4*)(mu + (size_t)g*512 + k0 + lcol);
    }
  };
  auto A_WRITE = [&](int buf){
    #pragma unroll
    for (int p=0; p<6; ++p){
      int r = p*32 + lrow;
      f32x4 v = ar[p];
      uint2 pk;
      pk.x = f2bf(v[0]) | (f2bf(v[1]) << 16);
      pk.y = f2bf(v[2]) | (f2bf(v[3]) << 16);
      *(uint2*)&As[buf][r*64 + (lcol ^ ((r&7)<<3))] = pk;
    }
  };
  auto B_ISSUE = [&](int ks, int buf){
    const int k0 = ks * 64;
    #pragma unroll
    for (int jj=0; jj<2; ++jj){
      int jb = w*2 + jj;
      int row = jb*8 + (lane>>3);
      int g = (row < 64) ? (f0 + row) : (448 + f0 + row);
      int srcc = ((lane&7) ^ ((lane>>3)&7)) * 8;
      gload16(wmixb + (size_t)g*512 + k0 + srcc, &Bs[buf][jb*512]);
    }
  };

  const f32x4 z4 = {0.f,0.f,0.f,0.f};
  f32x4 acc[3][4];
  #pragma unroll
  for (int d=0; d<3; ++d)
    #pragma unroll
    for (int nt=0; nt<4; ++nt) acc[d][nt] = z4;

  A_LOAD(0); B_ISSUE(0, 0); A_WRITE(0);
  for (int ks=0; ks<8; ++ks){
    const int cur = ks & 1;
    __syncthreads();
    if (ks < 7){ A_LOAD(ks+1); B_ISSUE(ks+1, cur^1); }
    #pragma unroll
    for (int kf=0; kf<2; ++kf){
      int kc = kf*32 + (lane>>4)*8;
      bf16x8 af[3];
      #pragma unroll
      for (int d=0; d<3; ++d){
        int r = d*64 + wn*16 + (lane&15);
        af[d] = *(const bf16x8*)&As[cur][r*64 + (kc ^ ((r&7)<<3))];
      }
      #pragma unroll
      for (int nt=0; nt<4; ++nt){
        int ntg = wf*2 + (nt&1) + (nt>>1)*4;
        int rr = ntg*16 + (lane&15);
        bf16x8 bf = *(const bf16x8*)&Bs[cur][rr*64 + (kc ^ ((rr&7)<<3))];
        #pragma unroll
        for (int d=0; d<3; ++d)
          acc[d][nt] = mfma16(bf, af[d], acc[d][nt]);
      }
    }
    if (ks < 7) A_WRITE(cur^1);
  }

  const int rb4 = (lane >> 4) * 4;
  const int nthr = n0 + wn*16 + (lane & 15);
  if (nthr < NN){
    #pragma unroll
    for (int c=0; c<2; ++c){
      int f = f0 + (wf*2 + c)*16 + rb4;
      uint2 pkv, pkd, pw0, pw1, pw2;
      uint32_t vb[4], db[4], w0[4], w1[4], w2[4];
      #pragma unroll
      for (int p=0; p<4; ++p){
        float v0 = acc[0][c][p],   v1 = acc[1][c][p],   v2 = acc[2][c][p];
        float u0 = acc[0][c+2][p], u1 = acc[1][c+2][p], u2 = acc[2][c+2][p];
        float vn = sqrtf(v0*v0 + v1*v1 + v2*v2 + 1e-8f);
        float dt = v0*u0 + v1*u1 + v2*u2;
        vb[p] = f2bf(vn); db[p] = f2bf(dt);
        w0[p] = f2bf(u0); w1[p] = f2bf(u1); w2[p] = f2bf(u2);
      }
      pkv.x = vb[0] | (vb[1] << 16); pkv.y = vb[2] | (vb[3] << 16);
      pkd.x = db[0] | (db[1] << 16); pkd.y = db[2] | (db[3] << 16);
      pw0.x = w0[0] | (w0[1] << 16); pw0.y = w0[2] | (w0[3] << 16);
      pw1.x = w1[0] | (w1[1] << 16); pw1.y = w1[2] | (w1[3] << 16);
      pw2.x = w2[0] | (w2[1] << 16); pw2.y = w2[2] | (w2[3] << 16);
      *(uint2*)(qh + (size_t)nthr*1024 + f)       = pkv;
      *(uint2*)(qh + (size_t)nthr*1024 + 512 + f) = pkd;
      size_t mb = (size_t)nthr*1536 + f;
      *(uint2*)(mw16 + mb)        = pw0;
      *(uint2*)(mw16 + mb + 512)  = pw1;
      *(uint2*)(mw16 + mb + 1024) = pw2;
    }
  }
}

// ---------------- K2 v2 (round-7 proven): 512 threads ------------------------
__global__ __launch_bounds__(512, 4)
void k_gemm2(const float* __restrict__ q, const uint16_t* __restrict__ w1b,
             const float* __restrict__ b1, uint16_t* __restrict__ qh){
  __shared__ uint16_t A2[2][2048];    // 64x32, 2x4KB
  __shared__ uint16_t B2[2][16384];   // 512x32, 2x32KB
  const int tid  = threadIdx.x;
  const int lane = tid & 63;
  const int w    = tid >> 6;          // 0..7
  const int wm   = w >> 2;            // 0..1 (32-row half)
  const int wn   = w & 3;             // 0..3 (128-col quarter)
  const int n0   = blockIdx.x * 64;

  f32x4 qa;
  auto QA_LOAD = [&](int s){
    int k0 = s*32;
    int row = tid >> 3, ch = tid & 7;
    int nc = (n0 + row < NN) ? n0 + row : NN-1;
    qa = *(const f32x4*)(q + (size_t)nc*512 + k0 + ch*4);
  };
  auto QA_WRITE = [&](int buf){
    int row = tid >> 3, ch = tid & 7;
    uint2 pk;
    pk.x = f2bf(qa[0]) | (f2bf(qa[1]) << 16);
    pk.y = f2bf(qa[2]) | (f2bf(qa[3]) << 16);
    *(uint2*)&A2[buf][row*32 + (((ch>>1) ^ (row&3))<<3) + (ch&1)*4] = pk;
  };
  auto VA_ISSUE = [&](int s, int buf){
    if (w < 4){
      int k0v = (s-16)*32;
      int row = w*16 + (lane>>2);
      int nc = (n0 + row < NN) ? n0 + row : NN-1;
      int srcch = (lane&3) ^ (row&3);
      gload16(qh + (size_t)nc*1024 + k0v + srcch*8, &A2[buf][w*512]);
    }
  };
  auto B_ISSUE = [&](int s, int buf){
    int k0 = s*32;
    #pragma unroll
    for (int jj=0; jj<4; ++jj){
      int j = w*4 + jj;
      int row = j*16 + (lane>>2);
      int srcch = (lane&3) ^ (row&3);
      gload16(w1b + (size_t)row*1024 + k0 + srcch*8, &B2[buf][j*512]);
    }
  };

  const f32x4 z4 = {0.f,0.f,0.f,0.f};
  f32x4 acc2[2][8];
  #pragma unroll
  for (int mt=0; mt<2; ++mt)
    #pragma unroll
    for (int nt=0; nt<8; ++nt) acc2[mt][nt] = z4;

  QA_LOAD(0); B_ISSUE(0, 0); QA_WRITE(0);
  for (int s=0; s<32; ++s){
    const int cur = s & 1;
    __syncthreads();
    if (s < 31){
      if (s+1 < 16) QA_LOAD(s+1); else VA_ISSUE(s+1, cur^1);
      B_ISSUE(s+1, cur^1);
    }
    {
      int kc = (lane>>4)*8;
      bf16x8 a[2];
      #pragma unroll
      for (int mt=0; mt<2; ++mt){
        int r = wm*32 + mt*16 + (lane&15);
        a[mt] = *(const bf16x8*)&A2[cur][r*32 + (kc ^ ((r&3)<<3))];
      }
      #pragma unroll
      for (int nt=0; nt<8; ++nt){
        int rr = wn*128 + nt*16 + (lane&15);
        bf16x8 b = *(const bf16x8*)&B2[cur][rr*32 + (kc ^ ((rr&3)<<3))];
        acc2[0][nt] = mfma16(a[0], b, acc2[0][nt]);
        acc2[1][nt] = mfma16(a[1], b, acc2[1][nt]);
      }
    }
    if (s < 31 && s+1 < 16) QA_WRITE(cur^1);
  }

  const int rb4 = (lane >> 4) * 4;
  #pragma unroll
  for (int nt=0; nt<8; ++nt){
    int col = wn*128 + nt*16 + (lane&15);
    float bb = b1[col];
    #pragma unroll
    for (int mt=0; mt<2; ++mt)
      #pragma unroll
      for (int j=0; j<4; ++j){
        int n = n0 + wm*32 + mt*16 + rb4 + j;
        if (n < NN){
          float x = acc2[mt][nt][j] + bb;
          float sv = x / (1.f + __expf(-x));
          qh[(size_t)n*1024 + col] = (uint16_t)f2bf(sv);
        }
      }
  }
}

// ---------------- K3e: v8 schedule with single-burst stream issue ------------
// All 11 E-loads (bb/dt/q/mu/mw) issue at p0 right AFTER B1 -> B1 is older
// than streams, so p1's wait is vmcnt(11) (no stream drain). One age-2 drain
// at p2 (vmcnt 0) replaces v8's three staggered age-2/age-0 drains; p3..p7
// wait only on pure-L2 B prefetches. mw/dt kept as raw uint2 until epilogue
// (no compiler-inserted early waits). Waits: {it?4:0, 11, 0,0,0,0,0,0}.
// dt-clobber ordering unchanged vs v8. grid = 1563, 80KB LDS.
__global__ __launch_bounds__(512, 4)
void k_gemm3b(const float* __restrict__ q, const float* __restrict__ mu,
              const uint16_t* __restrict__ w2b, const float* __restrict__ b2,
              float* __restrict__ dout, const uint16_t* __restrict__ mw16){
  __shared__ uint16_t Hs[32*512];     // 32KB
  __shared__ uint16_t B3[2][12288];   // 2x24KB ring
  const int tid  = threadIdx.x;
  const int lane = tid & 63;
  const int w    = tid >> 6;
  const int wm   = w >> 2;
  const int wn   = w & 3;
  const int n0   = blockIdx.x * 32;
  const uint16_t* qh = (const uint16_t*)dout;
  float* mout = dout + (size_t)QWORDS;
  const int l15 = lane & 15;
  const int rb4 = (lane >> 4) * 4;
  const f32x4 z4 = {0.f,0.f,0.f,0.f};

  #pragma unroll
  for (int i=0; i<4; ++i){
    int row = w*4 + i;
    int nc2 = (n0 + row < NN) ? n0 + row : NN-1;
    gload16(qh + (size_t)nc2*1024 + (size_t)((lane ^ (row&7))*8), &Hs[row*512]);
  }

  auto B_ISSUE = [&](int it, int ks, uint16_t* slot){
    #pragma unroll
    for (int jj=0; jj<3; ++jj){
      int jx = w*3 + jj;
      int rr = jx*8 + (lane>>3);
      int s3 = rr >> 6, fi = rr & 63;
      int g = s3*512 + it*64 + fi;
      gload16(w2b + (size_t)g*512 + ks*64 + ((lane&7) ^ (rr&7))*8, slot + jx*512);
    }
  };
  B_ISSUE(0, 0, B3[0]);

  const int nthr = n0 + wm*16 + l15;
  const int nc   = nthr < NN ? nthr : NN-1;

  f32x4 qv, bbv[3], muv[3];
  uint2  du, mwu[3];
  int    fb = 0;
  f32x4  acc3[3];

#define K3_MFMA(KS) do{ \
    const uint16_t* bsl = B3[(KS)&1]; \
    __builtin_amdgcn_s_setprio(1); \
    _Pragma("unroll") \
    for (int kf=0; kf<2; ++kf){ \
      int r = wm*16 + l15; \
      int ch = ((KS)*8 + kf*4 + (lane>>4)) ^ (r&7); \
      bf16x8 a = *(const bf16x8*)&Hs[r*512 + ch*8]; \
      _Pragma("unroll") \
      for (int s3=0; s3<3; ++s3){ \
        int rr = s3*64 + wn*16 + l15; \
        int chb = (kf*4 + (lane>>4)) ^ (rr&7); \
        bf16x8 b = *(const bf16x8*)&bsl[rr*64 + chb*8]; \
        acc3[s3] = mfma16(b, a, acc3[s3]); \
      } \
    } \
    __builtin_amdgcn_s_setprio(0); \
  } while(0)

  #pragma unroll 1
  for (int it=0; it<8; ++it){
    // ---- p0: wait B0; issue B1 then ALL streams ----
    if (it) { asm volatile("s_waitcnt vmcnt(4)" ::: "memory"); }
    else    { asm volatile("s_waitcnt vmcnt(0)" ::: "memory"); }
    __builtin_amdgcn_s_barrier();
    B_ISSUE(it, 1, B3[1]);
    FENCE();
    {
      #pragma unroll
      for (int s3=0; s3<3; ++s3) acc3[s3] = z4;
      fb = it*64 + wn*16 + rb4;
      bbv[0] = *(const f32x4*)(b2 + fb);
      bbv[1] = *(const f32x4*)(b2 + 512 + fb);
      bbv[2] = *(const f32x4*)(b2 + 1024 + fb);
      du = *(const uint2*)(qh + (size_t)nc*1024 + 512 + fb);
      qv = *(const f32x4*)(q + (size_t)nc*512 + fb);
      size_t mb = (size_t)nc*1536 + fb;
      muv[0] = *(const f32x4*)(mu + mb);
      muv[1] = *(const f32x4*)(mu + mb + 512);
      muv[2] = *(const f32x4*)(mu + mb + 1024);
      mwu[0] = *(const uint2*)(mw16 + mb);
      mwu[1] = *(const uint2*)(mw16 + mb + 512);
      mwu[2] = *(const uint2*)(mw16 + mb + 1024);
    }
    FENCE();
    K3_MFMA(0);

    // ---- p1: wait B1 (streams newer -> untouched) ----
    asm volatile("s_waitcnt vmcnt(11)" ::: "memory");
    __builtin_amdgcn_s_barrier();
    B_ISSUE(it, 2, B3[0]);
    FENCE();
    K3_MFMA(1);

    // ---- p2: single stream drain (age 2 phases) + B2 ----
    asm volatile("s_waitcnt vmcnt(0)" ::: "memory");
    __builtin_amdgcn_s_barrier();
    B_ISSUE(it, 3, B3[1]);
    FENCE();
    K3_MFMA(2);

    // ---- p3..p6: pure-L2 B waits ----
    asm volatile("s_waitcnt vmcnt(0)" ::: "memory");
    __builtin_amdgcn_s_barrier();
    B_ISSUE(it, 4, B3[0]);
    FENCE();
    K3_MFMA(3);

    asm volatile("s_waitcnt vmcnt(0)" ::: "memory");
    __builtin_amdgcn_s_barrier();
    B_ISSUE(it, 5, B3[1]);
    FENCE();
    K3_MFMA(4);

    asm volatile("s_waitcnt vmcnt(0)" ::: "memory");
    __builtin_amdgcn_s_barrier();
    B_ISSUE(it, 6, B3[0]);
    FENCE();
    K3_MFMA(5);

    asm volatile("s_waitcnt vmcnt(0)" ::: "memory");
    __builtin_amdgcn_s_barrier();
    B_ISSUE(it, 7, B3[1]);
    FENCE();
    K3_MFMA(6);

    // ---- p7 ----
    asm volatile("s_waitcnt vmcnt(0)" ::: "memory");
    __builtin_amdgcn_s_barrier();
    if (it < 7) B_ISSUE(it+1, 0, B3[0]);
    FENCE();
    K3_MFMA(7);
    if (nthr < NN){
      f32x4 qo, m0, m1, m2;
      #pragma unroll
      for (int p=0; p<4; ++p){
        uint32_t dh = (p & 2) ? du.y : du.x;
        float dtp = bf2f((p & 1) ? (dh >> 16) : (dh & 0xffffu));
        uint32_t w0h = (p & 2) ? mwu[0].y : mwu[0].x;
        uint32_t w1h = (p & 2) ? mwu[1].y : mwu[1].x;
        uint32_t w2h = (p & 2) ? mwu[2].y : mwu[2].x;
        float mw0 = bf2f((p & 1) ? (w0h >> 16) : (w0h & 0xffffu));
        float mw1 = bf2f((p & 1) ? (w1h >> 16) : (w1h & 0xffffu));
        float mw2 = bf2f((p & 1) ? (w2h >> 16) : (w2h & 0xffffu));
        float x0 = acc3[0][p] + bbv[0][p];
        float x1 = acc3[1][p] + bbv[1][p];
        float x2 = acc3[2][p] + bbv[2][p];
        qo[p] = qv[p] + x0 + x2*dtp;
        m0[p] = muv[0][p] + x1*mw0;
        m1[p] = muv[1][p] + x1*mw1;
        m2[p] = muv[2][p] + x1*mw2;
      }
      *(f32x4*)(dout + (size_t)nthr*512 + fb) = qo;
      size_t mb = (size_t)nthr*1536 + fb;
      *(f32x4*)(mout + mb)        = m0;
      *(f32x4*)(mout + mb + 512)  = m1;
      *(f32x4*)(mout + mb + 1024) = m2;
    }
  }
#undef K3_MFMA
}

// ---------------- K3 (fallback, round-8): f32 muW in-place -------------------
__global__ __launch_bounds__(512, 4)
void k_gemm3(const float* __restrict__ q, const float* __restrict__ mu,
             const uint16_t* __restrict__ w2b, const float* __restrict__ b2,
             float* __restrict__ dout){
  __shared__ uint16_t Hs[32*512];     // 32KB
  __shared__ uint16_t B3[2][12288];   // 2x24KB ring
  const int tid  = threadIdx.x;
  const int lane = tid & 63;
  const int w    = tid >> 6;
  const int wm   = w >> 2;
  const int wn   = w & 3;
  const int n0   = blockIdx.x * 32;
  const uint16_t* qh = (const uint16_t*)dout;
  float* mout = dout + (size_t)QWORDS;
  const int l15 = lane & 15;
  const int rb4 = (lane >> 4) * 4;
  const f32x4 z4 = {0.f,0.f,0.f,0.f};

  #pragma unroll
  for (int i=0; i<4; ++i){
    int row = w*4 + i;
    int nc2 = (n0 + row < NN) ? n0 + row : NN-1;
    gload16(qh + (size_t)nc2*1024 + (size_t)((lane ^ (row&7))*8), &Hs[row*512]);
  }

  auto B_ISSUE = [&](int it, int ks, uint16_t* slot){
    #pragma unroll
    for (int jj=0; jj<3; ++jj){
      int jx = w*3 + jj;
      int rr = jx*8 + (lane>>3);
      int s3 = rr >> 6, fi = rr & 63;
      int g = s3*512 + it*64 + fi;
      gload16(w2b + (size_t)g*512 + ks*64 + ((lane&7) ^ (rr&7))*8, slot + jx*512);
    }
  };
  B_ISSUE(0, 0, B3[0]);

  const int nthr = n0 + wm*16 + l15;
  const int nc   = nthr < NN ? nthr : NN-1;

  f32x4 qv, bbv[3], muv[3], mwv[3];
  float dtv[4];
  int   fb = 0;
  f32x4 acc3[3];

#define K3_MFMA(KS) do{ \
    const uint16_t* bsl = B3[(KS)&1]; \
    __builtin_amdgcn_s_setprio(1); \
    _Pragma("unroll") \
    for (int kf=0; kf<2; ++kf){ \
      int r = wm*16 + l15; \
      int ch = ((KS)*8 + kf*4 + (lane>>4)) ^ (r&7); \
      bf16x8 a = *(const bf16x8*)&Hs[r*512 + ch*8]; \
      _Pragma("unroll") \
      for (int s3=0; s3<3; ++s3){ \
        int rr = s3*64 + wn*16 + l15; \
        int chb = (kf*4 + (lane>>4)) ^ (rr&7); \
        bf16x8 b = *(const bf16x8*)&bsl[rr*64 + chb*8]; \
        acc3[s3] = mfma16(b, a, acc3[s3]); \
      } \
    } \
    __builtin_amdgcn_s_setprio(0); \
  } while(0)

  #pragma unroll 1
  for (int it=0; it<8; ++it){
    if (it) { asm volatile("s_waitcnt vmcnt(4)" ::: "memory"); }
    else    { asm volatile("s_waitcnt vmcnt(0)" ::: "memory"); }
    __builtin_amdgcn_s_barrier();
    B_ISSUE(it, 1, B3[1]);
    FENCE();
    {
      #pragma unroll
      for (int s3=0; s3<3; ++s3) acc3[s3] = z4;
      fb = it*64 + wn*16 + rb4;
      bbv[0] = *(const f32x4*)(b2 + fb);
      bbv[1] = *(const f32x4*)(b2 + 512 + fb);
      bbv[2] = *(const f32x4*)(b2 + 1024 + fb);
      uint2 du = *(const uint2*)(qh + (size_t)nc*1024 + 512 + fb);
      dtv[0] = bf2f(du.x & 0xffff); dtv[1] = bf2f(du.x >> 16);
      dtv[2] = bf2f(du.y & 0xffff); dtv[3] = bf2f(du.y >> 16);
      qv = *(const f32x4*)(q + (size_t)nc*512 + fb);
    }
    FENCE();
    K3_MFMA(0);

    asm volatile("s_waitcnt vmcnt(5)" ::: "memory");
    __builtin_amdgcn_s_barrier();
    B_ISSUE(it, 2, B3[0]);
    FENCE();
    {
      size_t mb = (size_t)nc*1536 + fb;
      muv[0] = *(const f32x4*)(mu + mb);
      muv[1] = *(const f32x4*)(mu + mb + 512);
      muv[2] = *(const f32x4*)(mu + mb + 1024);
    }
    FENCE();
    K3_MFMA(1);

    asm volatile("s_waitcnt vmcnt(3)" ::: "memory");
    __builtin_amdgcn_s_barrier();
    B_ISSUE(it, 3, B3[1]);
    FENCE();
    {
      size_t mb = (size_t)nc*1536 + fb;
      mwv[0] = *(const f32x4*)(mout + mb);
      mwv[1] = *(const f32x4*)(mout + mb + 512);
      mwv[2] = *(const f32x4*)(mout + mb + 1024);
    }
    FENCE();
    K3_MFMA(2);

    asm volatile("s_waitcnt vmcnt(3)" ::: "memory");
    __builtin_amdgcn_s_barrier();
    B_ISSUE(it, 4, B3[0]);
    FENCE();
    K3_MFMA(3);

    asm volatile("s_waitcnt vmcnt(0)" ::: "memory");
    __builtin_amdgcn_s_barrier();
    B_ISSUE(it, 5, B3[1]);
    FENCE();
    K3_MFMA(4);

    asm volatile("s_waitcnt vmcnt(0)" ::: "memory");
    __builtin_amdgcn_s_barrier();
    B_ISSUE(it, 6, B3[0]);
    FENCE();
    K3_MFMA(5);

    asm volatile("s_waitcnt vmcnt(0)" ::: "memory");
    __builtin_amdgcn_s_barrier();
    B_ISSUE(it, 7, B3[1]);
    FENCE();
    K3_MFMA(6);

    asm volatile("s_waitcnt vmcnt(0)" ::: "memory");
    __builtin_amdgcn_s_barrier();
    if (it < 7) B_ISSUE(it+1, 0, B3[0]);
    FENCE();
    K3_MFMA(7);
    if (nthr < NN){
      f32x4 qo, m0, m1, m2;
      #pragma unroll
      for (int p=0; p<4; ++p){
        float x0 = acc3[0][p] + bbv[0][p];
        float x1 = acc3[1][p] + bbv[1][p];
        float x2 = acc3[2][p] + bbv[2][p];
        qo[p] = qv[p] + x0 + x2*dtv[p];
        m0[p] = muv[0][p] + x1*mwv[0][p];
        m1[p] = muv[1][p] + x1*mwv[1][p];
        m2[p] = muv[2][p] + x1*mwv[2][p];
      }
      *(f32x4*)(dout + (size_t)nthr*512 + fb) = qo;
      size_t mb = (size_t)nthr*1536 + fb;
      *(f32x4*)(mout + mb)        = m0;
      *(f32x4*)(mout + mb + 512)  = m1;
      *(f32x4*)(mout + mb + 1024) = m2;
    }
  }
#undef K3_MFMA
}

extern "C" void kernel_launch(void* const* d_in, const int* in_sizes, int n_in,
                              void* d_out, int out_size, void* d_ws, size_t ws_size,
                              hipStream_t stream){
  (void)in_sizes; (void)n_in; (void)out_size;
  const float* q    = (const float*)d_in[0];
  const float* mu   = (const float*)d_in[1];
  const float* wmix = (const float*)d_in[2];
  const float* w1   = (const float*)d_in[3];
  const float* b1   = (const float*)d_in[4];
  const float* w2   = (const float*)d_in[5];
  const float* b2   = (const float*)d_in[6];
  uint16_t* wb = (uint16_t*)d_ws;
  float* dout = (float*)d_out;

  hipLaunchKernelGGL(k_convert, dim3(1792), dim3(256), 0, stream, wmix, w1, w2, wb);

  const size_t need = ((size_t)1835008 + (size_t)NN*1536) * 2;   // 157.3 MB
  if (ws_size >= need){
    uint16_t* mw16 = wb + 1835008;
    hipLaunchKernelGGL(k_gemm1b, dim3(6256), dim3(512), 0, stream,
                       mu, wb, (uint16_t*)d_out, mw16);
    hipLaunchKernelGGL(k_gemm2, dim3(782), dim3(512), 0, stream,
                       q, wb + 524288, b1, (uint16_t*)d_out);
    hipLaunchKernelGGL(k_gemm3b, dim3(1563), dim3(512), 0, stream,
                       q, mu, wb + 1048576, b2, dout, mw16);
  } else {
    hipLaunchKernelGGL(k_gemm1, dim3(6256), dim3(512), 0, stream,
                       mu, wb, (uint16_t*)d_out, dout + (size_t)QWORDS);
    hipLaunchKernelGGL(k_gemm2, dim3(782), dim3(512), 0, stream,
                       q, wb + 524288, b1, (uint16_t*)d_out);
    hipLaunchKernelGGL(k_gemm3, dim3(1563), dim3(512), 0, stream,
                       q, mu, wb + 1048576, b2, dout);
  }
}